// Round 1
// baseline (4504.192 us; speedup 1.0000x reference)
//
#include <hip/hip_runtime.h>

#define NN 100000
#define NE 1600000
#define D 64
#define TN 64  // nodes per linear-block

// ---------------- degree ----------------
__global__ __launch_bounds__(256) void deg_kernel(const int* __restrict__ dst,
                                                  float* __restrict__ deg, int nE) {
    int e = blockIdx.x * blockDim.x + threadIdx.x;
    if (e < nE) atomicAdd(&deg[dst[e]], 1.0f);
}

__global__ __launch_bounds__(256) void invdeg_kernel(float* __restrict__ deg, int n) {
    int i = blockIdx.x * blockDim.x + threadIdx.x;
    if (i < n) deg[i] = 1.0f / fmaxf(deg[i], 1.0f);
}

// ---------------- scatter-add: agg[dst] += x[src] ----------------
// 16 threads per edge, float4 per thread.
__global__ __launch_bounds__(256) void scatter_kernel(const float* __restrict__ x,
                                                      const int* __restrict__ src,
                                                      const int* __restrict__ dst,
                                                      float* __restrict__ agg, int nE) {
    long long idx = (long long)blockIdx.x * blockDim.x + threadIdx.x;
    int e = (int)(idx >> 4);
    int c4 = (int)(idx & 15);
    if (e >= nE) return;
    int s = src[e];
    int d = dst[e];
    float4 v = ((const float4*)x)[(long long)s * 16 + c4];
    float* o = agg + (long long)d * D + c4 * 4;
    atomicAdd(o + 0, v.x);
    atomicAdd(o + 1, v.y);
    atomicAdd(o + 2, v.z);
    atomicAdd(o + 3, v.w);
}

// ---------------- fused mean + dual-linear (+bias, relu) ----------------
// out[n][j] = relu( sum_k (agg[n][k]*invdeg[n]) * Wl[j][k] + bl[j]
//                 + sum_k x[n][k] * Wr[j][k] )
__global__ __launch_bounds__(256) void sage_linear_kernel(
    const float* __restrict__ agg, const float* __restrict__ invdeg,
    const float* __restrict__ x,
    const float* __restrict__ Wl, const float* __restrict__ bl,
    const float* __restrict__ Wr,
    float* __restrict__ out, int nNodes, int doRelu) {
    __shared__ float sWl[D][D + 1];  // transposed: sWl[k][j] = Wl[j*D+k]
    __shared__ float sWr[D][D + 1];
    __shared__ float sbl[D];
    __shared__ float sm[TN][D];
    __shared__ float sx[TN][D];

    int t = threadIdx.x;
    for (int i = t; i < D * D; i += 256) {
        int j = i >> 6, k = i & 63;
        sWl[k][j] = Wl[i];
        sWr[k][j] = Wr[i];
    }
    if (t < D) sbl[t] = bl[t];

    int n0 = blockIdx.x * TN;
    // stage tiles (coalesced float4); fold invdeg into mean tile
    for (int i = t; i < TN * D / 4; i += 256) {
        int n = i >> 4;
        int c4 = i & 15;
        int node = n0 + n;
        float4 a, b;
        if (node < nNodes) {
            a = ((const float4*)agg)[(long long)node * 16 + c4];
            float id = invdeg[node];
            a.x *= id; a.y *= id; a.z *= id; a.w *= id;
            b = ((const float4*)x)[(long long)node * 16 + c4];
        } else {
            a = make_float4(0.f, 0.f, 0.f, 0.f);
            b = a;
        }
        *((float4*)&sm[n][c4 * 4]) = a;
        *((float4*)&sx[n][c4 * 4]) = b;
    }
    __syncthreads();

    int j = t & 63;
    int nbase = t >> 6;  // 0..3
    for (int g = 0; g < TN / 4; ++g) {
        int n = nbase * (TN / 4) + g;
        int node = n0 + n;
        if (node >= nNodes) continue;
        float acc = sbl[j];
#pragma unroll
        for (int k = 0; k < D; ++k) {
            acc += sm[n][k] * sWl[k][j] + sx[n][k] * sWr[k][j];
        }
        if (doRelu) acc = fmaxf(acc, 0.f);
        out[(long long)node * D + j] = acc;
    }
}

extern "C" void kernel_launch(void* const* d_in, const int* in_sizes, int n_in,
                              void* d_out, int out_size, void* d_ws, size_t ws_size,
                              hipStream_t stream) {
    const float* x   = (const float*)d_in[0];
    const int*   src = (const int*)d_in[1];
    const int*   dst = (const int*)d_in[2];
    const float* Wl0 = (const float*)d_in[3];
    const float* bl0 = (const float*)d_in[4];
    const float* Wr0 = (const float*)d_in[5];
    const float* Wl1 = (const float*)d_in[6];
    const float* bl1 = (const float*)d_in[7];
    const float* Wr1 = (const float*)d_in[8];
    const float* Wl2 = (const float*)d_in[9];
    const float* bl2 = (const float*)d_in[10];
    const float* Wr2 = (const float*)d_in[11];
    float* out = (float*)d_out;

    const size_t featBytes = (size_t)NN * D * sizeof(float);  // 25.6 MB
    char* ws = (char*)d_ws;
    float* deg = (float*)ws;                                  // NN floats
    float* agg = (float*)(ws + (1 << 19));                    // 512 KiB offset
    float* h1  = (float*)(ws + (1 << 19) + featBytes);
    float* h2  = (float*)(ws + (1 << 19) + 2 * featBytes);

    // degree (once; shared across layers)
    hipMemsetAsync(deg, 0, (size_t)NN * sizeof(float), stream);
    deg_kernel<<<(NE + 255) / 256, 256, 0, stream>>>(dst, deg, NE);
    invdeg_kernel<<<(NN + 255) / 256, 256, 0, stream>>>(deg, NN);

    const int scatterGrid = (int)(((long long)NE * 16 + 255) / 256);
    const int linGrid = (NN + TN - 1) / TN;

    // layer 0
    hipMemsetAsync(agg, 0, featBytes, stream);
    scatter_kernel<<<scatterGrid, 256, 0, stream>>>(x, src, dst, agg, NE);
    sage_linear_kernel<<<linGrid, 256, 0, stream>>>(agg, deg, x, Wl0, bl0, Wr0, h1, NN, 1);

    // layer 1
    hipMemsetAsync(agg, 0, featBytes, stream);
    scatter_kernel<<<scatterGrid, 256, 0, stream>>>(h1, src, dst, agg, NE);
    sage_linear_kernel<<<linGrid, 256, 0, stream>>>(agg, deg, h1, Wl1, bl1, Wr1, h2, NN, 1);

    // layer 2
    hipMemsetAsync(agg, 0, featBytes, stream);
    scatter_kernel<<<scatterGrid, 256, 0, stream>>>(h2, src, dst, agg, NE);
    sage_linear_kernel<<<linGrid, 256, 0, stream>>>(agg, deg, h2, Wl2, bl2, Wr2, out, NN, 0);
}

// Round 2
// 919.169 us; speedup vs baseline: 4.9003x; 4.9003x over previous
//
#include <hip/hip_runtime.h>

#define NN 100000
#define NE 1600000
#define D 64
#define TN 64  // nodes per linear-block

// ---------------- CSR build ----------------
__global__ __launch_bounds__(256) void count_kernel(const int* __restrict__ dst,
                                                    int* __restrict__ counts, int nE) {
    int e = blockIdx.x * blockDim.x + threadIdx.x;
    if (e < nE) atomicAdd(&counts[dst[e]], 1);
}

// single-block exclusive scan of counts[0..n) -> rowptr[0..n], cursor copy
__global__ __launch_bounds__(1024) void scan_kernel(const int* __restrict__ counts,
                                                    int* __restrict__ rowptr,
                                                    int* __restrict__ cursor, int n) {
    __shared__ int s[1024];
    int t = threadIdx.x;
    int chunk = (n + 1023) / 1024;
    int lo = t * chunk;
    int hi = min(lo + chunk, n);
    int sum = 0;
    for (int i = lo; i < hi; ++i) sum += counts[i];
    s[t] = sum;
    __syncthreads();
    // Hillis-Steele inclusive scan
    for (int off = 1; off < 1024; off <<= 1) {
        int v = (t >= off) ? s[t - off] : 0;
        __syncthreads();
        s[t] += v;
        __syncthreads();
    }
    int base = s[t] - sum;  // exclusive
    for (int i = lo; i < hi; ++i) {
        rowptr[i] = base;
        cursor[i] = base;
        base += counts[i];
    }
    if (t == 1023) rowptr[n] = s[1023];
}

__global__ __launch_bounds__(256) void fill_kernel(const int* __restrict__ src,
                                                   const int* __restrict__ dst,
                                                   int* __restrict__ cursor,
                                                   int* __restrict__ esrc, int nE) {
    int e = blockIdx.x * blockDim.x + threadIdx.x;
    if (e < nE) {
        int pos = atomicAdd(&cursor[dst[e]], 1);
        esrc[pos] = src[e];
    }
}

// ---------------- pull-mode mean aggregation ----------------
// one wave (64 lanes) per node; 4 edges in flight (16 lanes x float4 each)
__global__ __launch_bounds__(256) void aggregate_kernel(const float* __restrict__ x,
                                                        const int* __restrict__ rowptr,
                                                        const int* __restrict__ esrc,
                                                        float* __restrict__ mean, int nNodes) {
    int node = (blockIdx.x * 256 + threadIdx.x) >> 6;
    if (node >= nNodes) return;
    int lane = threadIdx.x & 63;
    int g = lane >> 4;   // edge slot 0..3
    int q = lane & 15;   // float4 slot within the 64-channel row
    int rs = rowptr[node];
    int re = rowptr[node + 1];
    float ax = 0.f, ay = 0.f, az = 0.f, aw = 0.f;
    for (int i = rs + g; i < re; i += 4) {
        int s = esrc[i];
        float4 v = ((const float4*)x)[s * 16 + q];
        ax += v.x; ay += v.y; az += v.z; aw += v.w;
    }
    // reduce the 4 edge-slot partials (lanes l, l^16, l^32, l^48 share channels)
    ax += __shfl_xor(ax, 16, 64); ay += __shfl_xor(ay, 16, 64);
    az += __shfl_xor(az, 16, 64); aw += __shfl_xor(aw, 16, 64);
    ax += __shfl_xor(ax, 32, 64); ay += __shfl_xor(ay, 32, 64);
    az += __shfl_xor(az, 32, 64); aw += __shfl_xor(aw, 32, 64);
    if (g == 0) {
        float inv = 1.0f / fmaxf((float)(re - rs), 1.0f);
        float4 o;
        o.x = ax * inv; o.y = ay * inv; o.z = az * inv; o.w = aw * inv;
        ((float4*)mean)[node * 16 + q] = o;
    }
}

// ---------------- fused dual-linear (+bias, relu) ----------------
// out[n][j] = relu( sum_k mean[n][k]*Wl[j][k] + bl[j] + sum_k x[n][k]*Wr[j][k] )
__global__ __launch_bounds__(256) void sage_linear_kernel(
    const float* __restrict__ mean, const float* __restrict__ x,
    const float* __restrict__ Wl, const float* __restrict__ bl,
    const float* __restrict__ Wr,
    float* __restrict__ out, int nNodes, int doRelu) {
    __shared__ float sWl[D][D + 1];  // transposed: sWl[k][j] = Wl[j*D+k]
    __shared__ float sWr[D][D + 1];
    __shared__ float sbl[D];
    __shared__ float sm[TN][D];
    __shared__ float sx[TN][D];

    int t = threadIdx.x;
    for (int i = t; i < D * D; i += 256) {
        int j = i >> 6, k = i & 63;
        sWl[k][j] = Wl[i];
        sWr[k][j] = Wr[i];
    }
    if (t < D) sbl[t] = bl[t];

    int n0 = blockIdx.x * TN;
    for (int i = t; i < TN * D / 4; i += 256) {
        int n = i >> 4;
        int c4 = i & 15;
        int node = n0 + n;
        float4 a, b;
        if (node < nNodes) {
            a = ((const float4*)mean)[(long long)node * 16 + c4];
            b = ((const float4*)x)[(long long)node * 16 + c4];
        } else {
            a = make_float4(0.f, 0.f, 0.f, 0.f);
            b = a;
        }
        *((float4*)&sm[n][c4 * 4]) = a;
        *((float4*)&sx[n][c4 * 4]) = b;
    }
    __syncthreads();

    int j = t & 63;
    int nbase = t >> 6;  // 0..3
    for (int g = 0; g < TN / 4; ++g) {
        int n = nbase * (TN / 4) + g;
        int node = n0 + n;
        if (node >= nNodes) continue;
        float acc = sbl[j];
#pragma unroll
        for (int k = 0; k < D; ++k) {
            acc += sm[n][k] * sWl[k][j] + sx[n][k] * sWr[k][j];
        }
        if (doRelu) acc = fmaxf(acc, 0.f);
        out[(long long)node * D + j] = acc;
    }
}

extern "C" void kernel_launch(void* const* d_in, const int* in_sizes, int n_in,
                              void* d_out, int out_size, void* d_ws, size_t ws_size,
                              hipStream_t stream) {
    const float* x   = (const float*)d_in[0];
    const int*   src = (const int*)d_in[1];
    const int*   dst = (const int*)d_in[2];
    const float* Wl0 = (const float*)d_in[3];
    const float* bl0 = (const float*)d_in[4];
    const float* Wr0 = (const float*)d_in[5];
    const float* Wl1 = (const float*)d_in[6];
    const float* bl1 = (const float*)d_in[7];
    const float* Wr1 = (const float*)d_in[8];
    const float* Wl2 = (const float*)d_in[9];
    const float* bl2 = (const float*)d_in[10];
    const float* Wr2 = (const float*)d_in[11];
    float* out = (float*)d_out;

    const size_t featBytes = (size_t)NN * D * sizeof(float);  // 25.6 MB
    char* ws = (char*)d_ws;
    int*   counts = (int*)ws;                          // NN
    int*   rowptr = (int*)(ws + (1 << 19));            // NN+1
    int*   cursor = (int*)(ws + 2 * (1 << 19));        // NN
    int*   esrc   = (int*)(ws + 3 * (1 << 19));        // NE  (6.4 MB)
    char*  big    = ws + 3 * (1 << 19) + ((size_t)NE * 4 + 4096);
    float* mean = (float*)big;
    float* h1   = (float*)(big + featBytes);
    float* h2   = (float*)(big + 2 * featBytes);

    // CSR build (graph fixed; rebuilt deterministically each call)
    hipMemsetAsync(counts, 0, (size_t)NN * sizeof(int), stream);
    count_kernel<<<(NE + 255) / 256, 256, 0, stream>>>(dst, counts, NE);
    scan_kernel<<<1, 1024, 0, stream>>>(counts, rowptr, cursor, NN);
    fill_kernel<<<(NE + 255) / 256, 256, 0, stream>>>(src, dst, cursor, esrc, NE);

    const int aggGrid = (NN * 64 + 255) / 256;  // one wave per node
    const int linGrid = (NN + TN - 1) / TN;

    // layer 0
    aggregate_kernel<<<aggGrid, 256, 0, stream>>>(x, rowptr, esrc, mean, NN);
    sage_linear_kernel<<<linGrid, 256, 0, stream>>>(mean, x, Wl0, bl0, Wr0, h1, NN, 1);

    // layer 1
    aggregate_kernel<<<aggGrid, 256, 0, stream>>>(h1, rowptr, esrc, mean, NN);
    sage_linear_kernel<<<linGrid, 256, 0, stream>>>(mean, h1, Wl1, bl1, Wr1, h2, NN, 1);

    // layer 2
    aggregate_kernel<<<aggGrid, 256, 0, stream>>>(h2, rowptr, esrc, mean, NN);
    sage_linear_kernel<<<linGrid, 256, 0, stream>>>(mean, h2, Wl2, bl2, Wr2, out, NN, 0);
}

// Round 3
// 561.350 us; speedup vs baseline: 8.0239x; 1.6374x over previous
//
#include <hip/hip_runtime.h>

#define NN 100000
#define NE 1600000
#define D 64
#define TN 64  // nodes per linear-block
#define SCAN_B 256
#define SCAN_NB ((NN + SCAN_B - 1) / SCAN_B)  // 391

// ---------------- CSR build ----------------
__global__ __launch_bounds__(256) void count_kernel(const int* __restrict__ dst,
                                                    int* __restrict__ counts, int nE) {
    int e = blockIdx.x * blockDim.x + threadIdx.x;
    if (e < nE) atomicAdd(&counts[dst[e]], 1);
}

// hierarchical scan: (1) per-block sums
__global__ __launch_bounds__(SCAN_B) void scan_blocksum(const int* __restrict__ counts,
                                                        int* __restrict__ bsums, int n) {
    __shared__ int red[SCAN_B];
    int t = threadIdx.x;
    int i = blockIdx.x * SCAN_B + t;
    red[t] = (i < n) ? counts[i] : 0;
    __syncthreads();
    for (int off = SCAN_B / 2; off > 0; off >>= 1) {
        if (t < off) red[t] += red[t + off];
        __syncthreads();
    }
    if (t == 0) bsums[blockIdx.x] = red[0];
}

// (2) exclusive scan of the block sums (nb <= 512), also writes rowptr[n]=total
__global__ __launch_bounds__(512) void scan_bsums(int* __restrict__ bsums, int nb,
                                                  int* __restrict__ rowptr, int n) {
    __shared__ int s[512];
    int t = threadIdx.x;
    int v = (t < nb) ? bsums[t] : 0;
    s[t] = v;
    __syncthreads();
    for (int off = 1; off < 512; off <<= 1) {
        int u = (t >= off) ? s[t - off] : 0;
        __syncthreads();
        s[t] += u;
        __syncthreads();
    }
    if (t < nb) bsums[t] = s[t] - v;  // exclusive
    if (t == nb - 1) rowptr[n] = s[t];
}

// (3) per-block exclusive scan + base offset -> rowptr, cursor
__global__ __launch_bounds__(SCAN_B) void scan_final(const int* __restrict__ counts,
                                                     const int* __restrict__ bsums,
                                                     int* __restrict__ rowptr,
                                                     int* __restrict__ cursor, int n) {
    __shared__ int s[SCAN_B];
    int t = threadIdx.x;
    int i = blockIdx.x * SCAN_B + t;
    int v = (i < n) ? counts[i] : 0;
    s[t] = v;
    __syncthreads();
    for (int off = 1; off < SCAN_B; off <<= 1) {
        int u = (t >= off) ? s[t - off] : 0;
        __syncthreads();
        s[t] += u;
        __syncthreads();
    }
    int excl = s[t] - v + bsums[blockIdx.x];
    if (i < n) {
        rowptr[i] = excl;
        cursor[i] = excl;
    }
}

__global__ __launch_bounds__(256) void fill_kernel(const int* __restrict__ src,
                                                   const int* __restrict__ dst,
                                                   int* __restrict__ cursor,
                                                   int* __restrict__ esrc, int nE) {
    int e = blockIdx.x * blockDim.x + threadIdx.x;
    if (e < nE) {
        int pos = atomicAdd(&cursor[dst[e]], 1);
        esrc[pos] = src[e];
    }
}

// ---------------- pull-mode mean aggregation ----------------
// one wave (64 lanes) per node; 4 edges in flight (16 lanes x float4 each)
__global__ __launch_bounds__(256) void aggregate_kernel(const float* __restrict__ x,
                                                        const int* __restrict__ rowptr,
                                                        const int* __restrict__ esrc,
                                                        float* __restrict__ mean, int nNodes) {
    int node = (blockIdx.x * 256 + threadIdx.x) >> 6;
    if (node >= nNodes) return;
    int lane = threadIdx.x & 63;
    int g = lane >> 4;   // edge slot 0..3
    int q = lane & 15;   // float4 slot within the 64-channel row
    int rs = rowptr[node];
    int re = rowptr[node + 1];
    float ax = 0.f, ay = 0.f, az = 0.f, aw = 0.f;
    for (int i = rs + g; i < re; i += 4) {
        int s = esrc[i];
        float4 v = ((const float4*)x)[s * 16 + q];
        ax += v.x; ay += v.y; az += v.z; aw += v.w;
    }
    ax += __shfl_xor(ax, 16, 64); ay += __shfl_xor(ay, 16, 64);
    az += __shfl_xor(az, 16, 64); aw += __shfl_xor(aw, 16, 64);
    ax += __shfl_xor(ax, 32, 64); ay += __shfl_xor(ay, 32, 64);
    az += __shfl_xor(az, 32, 64); aw += __shfl_xor(aw, 32, 64);
    if (g == 0) {
        float inv = 1.0f / fmaxf((float)(re - rs), 1.0f);
        float4 o;
        o.x = ax * inv; o.y = ay * inv; o.z = az * inv; o.w = aw * inv;
        ((float4*)mean)[node * 16 + q] = o;
    }
}

// ---------------- fused dual-linear (+bias, relu), register-tiled ----------------
// thread tile: 4 nodes x 4 outputs. Per k: 2x ds_read_b128 (weights) + 8 broadcast b32.
__global__ __launch_bounds__(256) void sage_linear_kernel(
    const float* __restrict__ mean, const float* __restrict__ x,
    const float* __restrict__ Wl, const float* __restrict__ bl,
    const float* __restrict__ Wr,
    float* __restrict__ out, int nNodes, int doRelu) {
    __shared__ float sWl[D][D];      // transposed: sWl[k][j] = Wl[j*D+k]; rows 256B aligned
    __shared__ float sWr[D][D];
    __shared__ float sbl[D];
    __shared__ float sm[TN][D + 1];  // +1 pad: column reads hit distinct banks
    __shared__ float sx[TN][D + 1];

    int t = threadIdx.x;
    for (int i = t; i < D * D; i += 256) {
        int j = i >> 6, k = i & 63;
        sWl[k][j] = Wl[i];
        sWr[k][j] = Wr[i];
    }
    if (t < D) sbl[t] = bl[t];

    int n0 = blockIdx.x * TN;
    for (int i = t; i < TN * D / 4; i += 256) {
        int n = i >> 4;
        int c4 = i & 15;
        int node = n0 + n;
        float4 a, b;
        if (node < nNodes) {
            a = ((const float4*)mean)[(long long)node * 16 + c4];
            b = ((const float4*)x)[(long long)node * 16 + c4];
        } else {
            a = make_float4(0.f, 0.f, 0.f, 0.f);
            b = a;
        }
        sm[n][c4 * 4 + 0] = a.x; sm[n][c4 * 4 + 1] = a.y;
        sm[n][c4 * 4 + 2] = a.z; sm[n][c4 * 4 + 3] = a.w;
        sx[n][c4 * 4 + 0] = b.x; sx[n][c4 * 4 + 1] = b.y;
        sx[n][c4 * 4 + 2] = b.z; sx[n][c4 * 4 + 3] = b.w;
    }
    __syncthreads();

    int jq = t & 15;   // output quad: j0 = jq*4
    int nb = t >> 4;   // node quad: nodes nb*4 .. nb*4+3
    int j0 = jq * 4;
    float acc[4][4];
#pragma unroll
    for (int i = 0; i < 4; ++i)
#pragma unroll
        for (int jj = 0; jj < 4; ++jj) acc[i][jj] = 0.f;

#pragma unroll 4
    for (int k = 0; k < D; ++k) {
        float4 wl = *(const float4*)&sWl[k][j0];
        float4 wr = *(const float4*)&sWr[k][j0];
#pragma unroll
        for (int i = 0; i < 4; ++i) {
            float am = sm[nb * 4 + i][k];
            float av = sx[nb * 4 + i][k];
            acc[i][0] += am * wl.x + av * wr.x;
            acc[i][1] += am * wl.y + av * wr.y;
            acc[i][2] += am * wl.z + av * wr.z;
            acc[i][3] += am * wl.w + av * wr.w;
        }
    }

    float4 bias = *(const float4*)&sbl[j0];
#pragma unroll
    for (int i = 0; i < 4; ++i) {
        int node = n0 + nb * 4 + i;
        if (node >= nNodes) continue;
        float4 o;
        o.x = acc[i][0] + bias.x;
        o.y = acc[i][1] + bias.y;
        o.z = acc[i][2] + bias.z;
        o.w = acc[i][3] + bias.w;
        if (doRelu) {
            o.x = fmaxf(o.x, 0.f); o.y = fmaxf(o.y, 0.f);
            o.z = fmaxf(o.z, 0.f); o.w = fmaxf(o.w, 0.f);
        }
        ((float4*)out)[(long long)node * 16 + jq] = o;
    }
}

extern "C" void kernel_launch(void* const* d_in, const int* in_sizes, int n_in,
                              void* d_out, int out_size, void* d_ws, size_t ws_size,
                              hipStream_t stream) {
    const float* x   = (const float*)d_in[0];
    const int*   src = (const int*)d_in[1];
    const int*   dst = (const int*)d_in[2];
    const float* Wl0 = (const float*)d_in[3];
    const float* bl0 = (const float*)d_in[4];
    const float* Wr0 = (const float*)d_in[5];
    const float* Wl1 = (const float*)d_in[6];
    const float* bl1 = (const float*)d_in[7];
    const float* Wr1 = (const float*)d_in[8];
    const float* Wl2 = (const float*)d_in[9];
    const float* bl2 = (const float*)d_in[10];
    const float* Wr2 = (const float*)d_in[11];
    float* out = (float*)d_out;

    const size_t featBytes = (size_t)NN * D * sizeof(float);  // 25.6 MB
    char* ws = (char*)d_ws;
    int*   counts = (int*)ws;                                 // NN
    int*   rowptr = (int*)(ws + (1 << 19));                   // NN+1
    int*   cursor = (int*)(ws + 2 * (1 << 19));               // NN
    int*   bsums  = (int*)(ws + 3 * (1 << 19));               // SCAN_NB
    int*   esrc   = (int*)(ws + 3 * (1 << 19) + (1 << 16));   // NE (6.4 MB)
    char*  big    = ws + 8 * (1 << 20);
    float* mean = (float*)big;
    float* h1   = (float*)(big + featBytes);
    float* h2   = (float*)(big + 2 * featBytes);

    // CSR build (graph fixed; rebuilt deterministically each call)
    hipMemsetAsync(counts, 0, (size_t)NN * sizeof(int), stream);
    count_kernel<<<(NE + 255) / 256, 256, 0, stream>>>(dst, counts, NE);
    scan_blocksum<<<SCAN_NB, SCAN_B, 0, stream>>>(counts, bsums, NN);
    scan_bsums<<<1, 512, 0, stream>>>(bsums, SCAN_NB, rowptr, NN);
    scan_final<<<SCAN_NB, SCAN_B, 0, stream>>>(counts, bsums, rowptr, cursor, NN);
    fill_kernel<<<(NE + 255) / 256, 256, 0, stream>>>(src, dst, cursor, esrc, NE);

    const int aggGrid = (NN * 64 + 255) / 256;  // one wave per node
    const int linGrid = (NN + TN - 1) / TN;

    // layer 0
    aggregate_kernel<<<aggGrid, 256, 0, stream>>>(x, rowptr, esrc, mean, NN);
    sage_linear_kernel<<<linGrid, 256, 0, stream>>>(mean, x, Wl0, bl0, Wr0, h1, NN, 1);

    // layer 1
    aggregate_kernel<<<aggGrid, 256, 0, stream>>>(h1, rowptr, esrc, mean, NN);
    sage_linear_kernel<<<linGrid, 256, 0, stream>>>(mean, h1, Wl1, bl1, Wr1, h2, NN, 1);

    // layer 2
    aggregate_kernel<<<aggGrid, 256, 0, stream>>>(h2, rowptr, esrc, mean, NN);
    sage_linear_kernel<<<linGrid, 256, 0, stream>>>(mean, h2, Wl2, bl2, Wr2, out, NN, 0);
}

// Round 4
// 430.015 us; speedup vs baseline: 10.4745x; 1.3054x over previous
//
#include <hip/hip_runtime.h>

#define NN 100000
#define NE 1600000
#define D 64
#define TN 64  // nodes per linear-block
#define SCAN_B 256
#define SCAN_NB ((NN + SCAN_B - 1) / SCAN_B)  // 391

#define NBUCK ((NN + 255) / 256)              // 391 buckets of 256 nodes
#define EPB 4096                               // edges per partition block
#define P1_BLOCKS ((NE + EPB - 1) / EPB)       // 391
#define BCAP 6144                              // max edges per bucket (avg 4096, sigma 64)

// ---------------- CSR build: bucketed counting sort ----------------
// p0: histogram of dst>>8 into NBUCK global counters (LDS-aggregated)
__global__ __launch_bounds__(256) void p0_bucket_hist(const int* __restrict__ dst,
                                                      int* __restrict__ bucket_cnt, int nE) {
    __shared__ int h[NBUCK];
    int t = threadIdx.x;
    for (int i = t; i < NBUCK; i += 256) h[i] = 0;
    __syncthreads();
    int base = blockIdx.x * EPB;
    for (int i = t; i < EPB; i += 256) {
        int e = base + i;
        if (e < nE) atomicAdd(&h[dst[e] >> 8], 1);
    }
    __syncthreads();
    for (int i = t; i < NBUCK; i += 256)
        if (h[i]) atomicAdd(&bucket_cnt[i], h[i]);
}

// exclusive scan of bucket counts -> bucket_off[NBUCK+1], cursor copy
__global__ __launch_bounds__(512) void bucket_scan(const int* __restrict__ bucket_cnt,
                                                   int* __restrict__ bucket_off,
                                                   int* __restrict__ bucket_cur) {
    __shared__ int s[512];
    int t = threadIdx.x;
    int v = (t < NBUCK) ? bucket_cnt[t] : 0;
    s[t] = v;
    __syncthreads();
    for (int off = 1; off < 512; off <<= 1) {
        int u = (t >= off) ? s[t - off] : 0;
        __syncthreads();
        s[t] += u;
        __syncthreads();
    }
    if (t < NBUCK) { bucket_off[t] = s[t] - v; bucket_cur[t] = s[t] - v; }
    if (t == NBUCK - 1) bucket_off[NBUCK] = s[t];
}

// p1: scatter edges into bucket regions as packed (local_dst<<24)|src
__global__ __launch_bounds__(256) void p1_partition(const int* __restrict__ src,
                                                    const int* __restrict__ dst,
                                                    int* __restrict__ bucket_cur,
                                                    unsigned* __restrict__ packed, int nE) {
    __shared__ int h[NBUCK];
    int t = threadIdx.x;
    for (int i = t; i < NBUCK; i += 256) h[i] = 0;
    __syncthreads();
    int base = blockIdx.x * EPB;
    for (int i = t; i < EPB; i += 256) {
        int e = base + i;
        if (e < nE) atomicAdd(&h[dst[e] >> 8], 1);
    }
    __syncthreads();
    // reserve global ranges; h[b] becomes this block's running global cursor
    for (int i = t; i < NBUCK; i += 256) {
        int c = h[i];
        h[i] = c ? atomicAdd(&bucket_cur[i], c) : 0;
    }
    __syncthreads();
    for (int i = t; i < EPB; i += 256) {
        int e = base + i;
        if (e < nE) {
            int d = dst[e];
            int pos = atomicAdd(&h[d >> 8], 1);
            packed[pos] = ((unsigned)(d & 255) << 24) | (unsigned)src[e];
        }
    }
}

// p2a: per-bucket node histogram -> counts (coalesced write)
__global__ __launch_bounds__(256) void p2a_hist(const unsigned* __restrict__ packed,
                                                const int* __restrict__ bucket_off,
                                                int* __restrict__ counts, int nNodes) {
    __shared__ int h[256];
    int b = blockIdx.x, t = threadIdx.x;
    h[t] = 0;
    __syncthreads();
    int lo = bucket_off[b], hi = bucket_off[b + 1];
    for (int i = lo + t; i < hi; i += 256) atomicAdd(&h[packed[i] >> 24], 1);
    __syncthreads();
    int node = b * 256 + t;
    if (node < nNodes) counts[node] = h[t];
}

// p2b: in-LDS counting sort of each bucket; coalesced esrc write
__global__ __launch_bounds__(256) void p2b_place(const unsigned* __restrict__ packed,
                                                 const int* __restrict__ bucket_off,
                                                 int* __restrict__ esrc) {
    __shared__ int h[256];
    __shared__ int cur[256];
    __shared__ int sl[BCAP];
    int b = blockIdx.x, t = threadIdx.x;
    h[t] = 0;
    __syncthreads();
    int lo = bucket_off[b], hi = bucket_off[b + 1];
    int cnt = hi - lo;
    for (int i = lo + t; i < hi; i += 256) atomicAdd(&h[packed[i] >> 24], 1);
    __syncthreads();
    int v = h[t];
    for (int off = 1; off < 256; off <<= 1) {
        int u = (t >= off) ? h[t - off] : 0;
        __syncthreads();
        h[t] += u;
        __syncthreads();
    }
    cur[t] = h[t] - v;  // exclusive scan = local base
    __syncthreads();
    for (int i = lo + t; i < hi; i += 256) {
        unsigned p = packed[i];
        int pos = atomicAdd(&cur[p >> 24], 1);
        if (pos < BCAP) sl[pos] = (int)(p & 0xFFFFFFu);
    }
    __syncthreads();
    for (int i = t; i < cnt; i += 256) esrc[lo + i] = sl[i];
}

// ---------------- node-count scan (rowptr) ----------------
__global__ __launch_bounds__(SCAN_B) void scan_blocksum(const int* __restrict__ counts,
                                                        int* __restrict__ bsums, int n) {
    __shared__ int red[SCAN_B];
    int t = threadIdx.x;
    int i = blockIdx.x * SCAN_B + t;
    red[t] = (i < n) ? counts[i] : 0;
    __syncthreads();
    for (int off = SCAN_B / 2; off > 0; off >>= 1) {
        if (t < off) red[t] += red[t + off];
        __syncthreads();
    }
    if (t == 0) bsums[blockIdx.x] = red[0];
}

__global__ __launch_bounds__(512) void scan_bsums(int* __restrict__ bsums, int nb,
                                                  int* __restrict__ rowptr, int n) {
    __shared__ int s[512];
    int t = threadIdx.x;
    int v = (t < nb) ? bsums[t] : 0;
    s[t] = v;
    __syncthreads();
    for (int off = 1; off < 512; off <<= 1) {
        int u = (t >= off) ? s[t - off] : 0;
        __syncthreads();
        s[t] += u;
        __syncthreads();
    }
    if (t < nb) bsums[t] = s[t] - v;
    if (t == nb - 1) rowptr[n] = s[t];
}

__global__ __launch_bounds__(SCAN_B) void scan_final(const int* __restrict__ counts,
                                                     const int* __restrict__ bsums,
                                                     int* __restrict__ rowptr, int n) {
    __shared__ int s[SCAN_B];
    int t = threadIdx.x;
    int i = blockIdx.x * SCAN_B + t;
    int v = (i < n) ? counts[i] : 0;
    s[t] = v;
    __syncthreads();
    for (int off = 1; off < SCAN_B; off <<= 1) {
        int u = (t >= off) ? s[t - off] : 0;
        __syncthreads();
        s[t] += u;
        __syncthreads();
    }
    if (i < n) rowptr[i] = s[t] - v + bsums[blockIdx.x];
}

// ---------------- pull-mode mean aggregation ----------------
__global__ __launch_bounds__(256) void aggregate_kernel(const float* __restrict__ x,
                                                        const int* __restrict__ rowptr,
                                                        const int* __restrict__ esrc,
                                                        float* __restrict__ mean, int nNodes) {
    int node = (blockIdx.x * 256 + threadIdx.x) >> 6;
    if (node >= nNodes) return;
    int lane = threadIdx.x & 63;
    int g = lane >> 4;
    int q = lane & 15;
    int rs = rowptr[node];
    int re = rowptr[node + 1];
    float ax = 0.f, ay = 0.f, az = 0.f, aw = 0.f;
    for (int i = rs + g; i < re; i += 4) {
        int s = esrc[i];
        float4 v = ((const float4*)x)[s * 16 + q];
        ax += v.x; ay += v.y; az += v.z; aw += v.w;
    }
    ax += __shfl_xor(ax, 16, 64); ay += __shfl_xor(ay, 16, 64);
    az += __shfl_xor(az, 16, 64); aw += __shfl_xor(aw, 16, 64);
    ax += __shfl_xor(ax, 32, 64); ay += __shfl_xor(ay, 32, 64);
    az += __shfl_xor(az, 32, 64); aw += __shfl_xor(aw, 32, 64);
    if (g == 0) {
        float inv = 1.0f / fmaxf((float)(re - rs), 1.0f);
        float4 o;
        o.x = ax * inv; o.y = ay * inv; o.z = az * inv; o.w = aw * inv;
        ((float4*)mean)[node * 16 + q] = o;
    }
}

// ---------------- fused dual-linear (+bias, relu), register-tiled ----------------
__global__ __launch_bounds__(256) void sage_linear_kernel(
    const float* __restrict__ mean, const float* __restrict__ x,
    const float* __restrict__ Wl, const float* __restrict__ bl,
    const float* __restrict__ Wr,
    float* __restrict__ out, int nNodes, int doRelu) {
    __shared__ float sWl[D][D];
    __shared__ float sWr[D][D];
    __shared__ float sbl[D];
    __shared__ float sm[TN][D + 1];
    __shared__ float sx[TN][D + 1];

    int t = threadIdx.x;
    for (int i = t; i < D * D; i += 256) {
        int j = i >> 6, k = i & 63;
        sWl[k][j] = Wl[i];
        sWr[k][j] = Wr[i];
    }
    if (t < D) sbl[t] = bl[t];

    int n0 = blockIdx.x * TN;
    for (int i = t; i < TN * D / 4; i += 256) {
        int n = i >> 4;
        int c4 = i & 15;
        int node = n0 + n;
        float4 a, b;
        if (node < nNodes) {
            a = ((const float4*)mean)[(long long)node * 16 + c4];
            b = ((const float4*)x)[(long long)node * 16 + c4];
        } else {
            a = make_float4(0.f, 0.f, 0.f, 0.f);
            b = a;
        }
        sm[n][c4 * 4 + 0] = a.x; sm[n][c4 * 4 + 1] = a.y;
        sm[n][c4 * 4 + 2] = a.z; sm[n][c4 * 4 + 3] = a.w;
        sx[n][c4 * 4 + 0] = b.x; sx[n][c4 * 4 + 1] = b.y;
        sx[n][c4 * 4 + 2] = b.z; sx[n][c4 * 4 + 3] = b.w;
    }
    __syncthreads();

    int jq = t & 15;
    int nb = t >> 4;
    int j0 = jq * 4;
    float acc[4][4];
#pragma unroll
    for (int i = 0; i < 4; ++i)
#pragma unroll
        for (int jj = 0; jj < 4; ++jj) acc[i][jj] = 0.f;

#pragma unroll 4
    for (int k = 0; k < D; ++k) {
        float4 wl = *(const float4*)&sWl[k][j0];
        float4 wr = *(const float4*)&sWr[k][j0];
#pragma unroll
        for (int i = 0; i < 4; ++i) {
            float am = sm[nb * 4 + i][k];
            float av = sx[nb * 4 + i][k];
            acc[i][0] += am * wl.x + av * wr.x;
            acc[i][1] += am * wl.y + av * wr.y;
            acc[i][2] += am * wl.z + av * wr.z;
            acc[i][3] += am * wl.w + av * wr.w;
        }
    }

    float4 bias = *(const float4*)&sbl[j0];
#pragma unroll
    for (int i = 0; i < 4; ++i) {
        int node = n0 + nb * 4 + i;
        if (node >= nNodes) continue;
        float4 o;
        o.x = acc[i][0] + bias.x;
        o.y = acc[i][1] + bias.y;
        o.z = acc[i][2] + bias.z;
        o.w = acc[i][3] + bias.w;
        if (doRelu) {
            o.x = fmaxf(o.x, 0.f); o.y = fmaxf(o.y, 0.f);
            o.z = fmaxf(o.z, 0.f); o.w = fmaxf(o.w, 0.f);
        }
        ((float4*)out)[(long long)node * 16 + jq] = o;
    }
}

extern "C" void kernel_launch(void* const* d_in, const int* in_sizes, int n_in,
                              void* d_out, int out_size, void* d_ws, size_t ws_size,
                              hipStream_t stream) {
    const float* x   = (const float*)d_in[0];
    const int*   src = (const int*)d_in[1];
    const int*   dst = (const int*)d_in[2];
    const float* Wl0 = (const float*)d_in[3];
    const float* bl0 = (const float*)d_in[4];
    const float* Wr0 = (const float*)d_in[5];
    const float* Wl1 = (const float*)d_in[6];
    const float* bl1 = (const float*)d_in[7];
    const float* Wr1 = (const float*)d_in[8];
    const float* Wl2 = (const float*)d_in[9];
    const float* bl2 = (const float*)d_in[10];
    const float* Wr2 = (const float*)d_in[11];
    float* out = (float*)d_out;

    const size_t featBytes = (size_t)NN * D * sizeof(float);  // 25.6 MB
    char* ws = (char*)d_ws;
    int* bucket_cnt = (int*)(ws);                    // NBUCK
    int* bucket_off = (int*)(ws + (16 << 10));       // NBUCK+1
    int* bucket_cur = (int*)(ws + (32 << 10));       // NBUCK
    int* bsums      = (int*)(ws + (48 << 10));       // SCAN_NB
    int* counts     = (int*)(ws + (1 << 20));        // NN
    int* rowptr     = (int*)(ws + (1 << 20) + (512 << 10));  // NN+1
    int* esrc       = (int*)(ws + (2 << 20));        // NE (6.4 MB)
    char* big = ws + (9 << 20);
    float* mean = (float*)big;                        // 25.6 MB
    unsigned* packed = (unsigned*)big;                // aliases mean (dead until agg)
    float* h1 = (float*)(big + featBytes);
    float* h2 = (float*)(big + 2 * featBytes);

    // ---- CSR build (bucketed counting sort; no per-edge global atomics) ----
    hipMemsetAsync(bucket_cnt, 0, (size_t)NBUCK * sizeof(int), stream);
    p0_bucket_hist<<<P1_BLOCKS, 256, 0, stream>>>(dst, bucket_cnt, NE);
    bucket_scan<<<1, 512, 0, stream>>>(bucket_cnt, bucket_off, bucket_cur);
    p1_partition<<<P1_BLOCKS, 256, 0, stream>>>(src, dst, bucket_cur, packed, NE);
    p2a_hist<<<NBUCK, 256, 0, stream>>>(packed, bucket_off, counts, NN);
    scan_blocksum<<<SCAN_NB, SCAN_B, 0, stream>>>(counts, bsums, NN);
    scan_bsums<<<1, 512, 0, stream>>>(bsums, SCAN_NB, rowptr, NN);
    scan_final<<<SCAN_NB, SCAN_B, 0, stream>>>(counts, bsums, rowptr, NN);
    p2b_place<<<NBUCK, 256, 0, stream>>>(packed, bucket_off, esrc);

    const int aggGrid = (NN * 64 + 255) / 256;
    const int linGrid = (NN + TN - 1) / TN;

    // layer 0
    aggregate_kernel<<<aggGrid, 256, 0, stream>>>(x, rowptr, esrc, mean, NN);
    sage_linear_kernel<<<linGrid, 256, 0, stream>>>(mean, x, Wl0, bl0, Wr0, h1, NN, 1);

    // layer 1
    aggregate_kernel<<<aggGrid, 256, 0, stream>>>(h1, rowptr, esrc, mean, NN);
    sage_linear_kernel<<<linGrid, 256, 0, stream>>>(mean, h1, Wl1, bl1, Wr1, h2, NN, 1);

    // layer 2
    aggregate_kernel<<<aggGrid, 256, 0, stream>>>(h2, rowptr, esrc, mean, NN);
    sage_linear_kernel<<<linGrid, 256, 0, stream>>>(mean, h2, Wl2, bl2, Wr2, out, NN, 0);
}

// Round 5
// 378.520 us; speedup vs baseline: 11.8995x; 1.1360x over previous
//
#include <hip/hip_runtime.h>

#define NN 100000
#define NE 1600000
#define D 64
#define TN 64  // nodes per linear-block
#define SCAN_B 256
#define SCAN_NB ((NN + SCAN_B - 1) / SCAN_B)  // 391

#define NBUCK ((NN + 255) / 256)              // 391 buckets of 256 nodes
#define EPB 4096                               // edges per partition block
#define P1_BLOCKS ((NE + EPB - 1) / EPB)       // 391
#define BCAP 6144                              // max edges per bucket

__device__ __forceinline__ unsigned short f2bf(float f) {
    unsigned u = __float_as_uint(f);
    u = (u + 0x7FFFu + ((u >> 16) & 1u)) >> 16;  // round-to-nearest-even
    return (unsigned short)u;
}

// ---------------- CSR build: bucketed counting sort ----------------
__global__ __launch_bounds__(256) void p0_bucket_hist(const int* __restrict__ dst,
                                                      int* __restrict__ bucket_cnt, int nE) {
    __shared__ int h[NBUCK];
    int t = threadIdx.x;
    for (int i = t; i < NBUCK; i += 256) h[i] = 0;
    __syncthreads();
    int base = blockIdx.x * EPB;
    for (int i = t; i < EPB; i += 256) {
        int e = base + i;
        if (e < nE) atomicAdd(&h[dst[e] >> 8], 1);
    }
    __syncthreads();
    for (int i = t; i < NBUCK; i += 256)
        if (h[i]) atomicAdd(&bucket_cnt[i], h[i]);
}

__global__ __launch_bounds__(512) void bucket_scan(const int* __restrict__ bucket_cnt,
                                                   int* __restrict__ bucket_off,
                                                   int* __restrict__ bucket_cur) {
    __shared__ int s[512];
    int t = threadIdx.x;
    int v = (t < NBUCK) ? bucket_cnt[t] : 0;
    s[t] = v;
    __syncthreads();
    for (int off = 1; off < 512; off <<= 1) {
        int u = (t >= off) ? s[t - off] : 0;
        __syncthreads();
        s[t] += u;
        __syncthreads();
    }
    if (t < NBUCK) { bucket_off[t] = s[t] - v; bucket_cur[t] = s[t] - v; }
    if (t == NBUCK - 1) bucket_off[NBUCK] = s[t];
}

__global__ __launch_bounds__(256) void p1_partition(const int* __restrict__ src,
                                                    const int* __restrict__ dst,
                                                    int* __restrict__ bucket_cur,
                                                    unsigned* __restrict__ packed, int nE) {
    __shared__ int h[NBUCK];
    int t = threadIdx.x;
    for (int i = t; i < NBUCK; i += 256) h[i] = 0;
    __syncthreads();
    int base = blockIdx.x * EPB;
    for (int i = t; i < EPB; i += 256) {
        int e = base + i;
        if (e < nE) atomicAdd(&h[dst[e] >> 8], 1);
    }
    __syncthreads();
    for (int i = t; i < NBUCK; i += 256) {
        int c = h[i];
        h[i] = c ? atomicAdd(&bucket_cur[i], c) : 0;
    }
    __syncthreads();
    for (int i = t; i < EPB; i += 256) {
        int e = base + i;
        if (e < nE) {
            int d = dst[e];
            int pos = atomicAdd(&h[d >> 8], 1);
            packed[pos] = ((unsigned)(d & 255) << 24) | (unsigned)src[e];
        }
    }
}

__global__ __launch_bounds__(256) void p2a_hist(const unsigned* __restrict__ packed,
                                                const int* __restrict__ bucket_off,
                                                int* __restrict__ counts, int nNodes) {
    __shared__ int h[256];
    int b = blockIdx.x, t = threadIdx.x;
    h[t] = 0;
    __syncthreads();
    int lo = bucket_off[b], hi = bucket_off[b + 1];
    for (int i = lo + t; i < hi; i += 256) atomicAdd(&h[packed[i] >> 24], 1);
    __syncthreads();
    int node = b * 256 + t;
    if (node < nNodes) counts[node] = h[t];
}

__global__ __launch_bounds__(256) void p2b_place(const unsigned* __restrict__ packed,
                                                 const int* __restrict__ bucket_off,
                                                 int* __restrict__ esrc) {
    __shared__ int h[256];
    __shared__ int cur[256];
    __shared__ int sl[BCAP];
    int b = blockIdx.x, t = threadIdx.x;
    h[t] = 0;
    __syncthreads();
    int lo = bucket_off[b], hi = bucket_off[b + 1];
    int cnt = hi - lo;
    for (int i = lo + t; i < hi; i += 256) atomicAdd(&h[packed[i] >> 24], 1);
    __syncthreads();
    int v = h[t];
    for (int off = 1; off < 256; off <<= 1) {
        int u = (t >= off) ? h[t - off] : 0;
        __syncthreads();
        h[t] += u;
        __syncthreads();
    }
    cur[t] = h[t] - v;
    __syncthreads();
    for (int i = lo + t; i < hi; i += 256) {
        unsigned p = packed[i];
        int pos = atomicAdd(&cur[p >> 24], 1);
        if (pos < BCAP) sl[pos] = (int)(p & 0xFFFFFFu);
    }
    __syncthreads();
    for (int i = t; i < cnt; i += 256) esrc[lo + i] = sl[i];
}

// ---------------- node-count scan (rowptr) ----------------
__global__ __launch_bounds__(SCAN_B) void scan_blocksum(const int* __restrict__ counts,
                                                        int* __restrict__ bsums, int n) {
    __shared__ int red[SCAN_B];
    int t = threadIdx.x;
    int i = blockIdx.x * SCAN_B + t;
    red[t] = (i < n) ? counts[i] : 0;
    __syncthreads();
    for (int off = SCAN_B / 2; off > 0; off >>= 1) {
        if (t < off) red[t] += red[t + off];
        __syncthreads();
    }
    if (t == 0) bsums[blockIdx.x] = red[0];
}

__global__ __launch_bounds__(512) void scan_bsums(int* __restrict__ bsums, int nb,
                                                  int* __restrict__ rowptr, int n) {
    __shared__ int s[512];
    int t = threadIdx.x;
    int v = (t < nb) ? bsums[t] : 0;
    s[t] = v;
    __syncthreads();
    for (int off = 1; off < 512; off <<= 1) {
        int u = (t >= off) ? s[t - off] : 0;
        __syncthreads();
        s[t] += u;
        __syncthreads();
    }
    if (t < nb) bsums[t] = s[t] - v;
    if (t == nb - 1) rowptr[n] = s[t];
}

__global__ __launch_bounds__(SCAN_B) void scan_final(const int* __restrict__ counts,
                                                     const int* __restrict__ bsums,
                                                     int* __restrict__ rowptr, int n) {
    __shared__ int s[SCAN_B];
    int t = threadIdx.x;
    int i = blockIdx.x * SCAN_B + t;
    int v = (i < n) ? counts[i] : 0;
    s[t] = v;
    __syncthreads();
    for (int off = 1; off < SCAN_B; off <<= 1) {
        int u = (t >= off) ? s[t - off] : 0;
        __syncthreads();
        s[t] += u;
        __syncthreads();
    }
    if (i < n) rowptr[i] = s[t] - v + bsums[blockIdx.x];
}

// ---------------- fp32 -> bf16 table convert ----------------
__global__ __launch_bounds__(256) void f2bf_kernel(const float* __restrict__ in,
                                                   unsigned short* __restrict__ out, int n4) {
    int i = blockIdx.x * 256 + threadIdx.x;
    if (i < n4) {
        float4 v = ((const float4*)in)[i];
        ushort4 o;
        o.x = f2bf(v.x); o.y = f2bf(v.y); o.z = f2bf(v.z); o.w = f2bf(v.w);
        ((ushort4*)out)[i] = o;
    }
}

// ---------------- pull-mode mean aggregation (bf16 gather, fp32 accum) ----------------
// one wave per node; 8 edge slots x 8 lanes x uint4(16B = 8 bf16 channels)
__global__ __launch_bounds__(256) void aggregate_bf16(const unsigned short* __restrict__ xb,
                                                      const int* __restrict__ rowptr,
                                                      const int* __restrict__ esrc,
                                                      float* __restrict__ mean, int nNodes) {
    int node = (blockIdx.x * 256 + threadIdx.x) >> 6;
    if (node >= nNodes) return;
    int lane = threadIdx.x & 63;
    int g = lane >> 3;  // edge slot 0..7
    int q = lane & 7;   // channel group: channels 8q..8q+7
    int rs = rowptr[node];
    int re = rowptr[node + 1];
    float a0 = 0, a1 = 0, a2 = 0, a3 = 0, a4 = 0, a5 = 0, a6 = 0, a7 = 0;
    for (int i = rs + g; i < re; i += 8) {
        int s = esrc[i];
        uint4 w = ((const uint4*)xb)[s * 8 + q];
        a0 += __uint_as_float(w.x << 16);
        a1 += __uint_as_float(w.x & 0xFFFF0000u);
        a2 += __uint_as_float(w.y << 16);
        a3 += __uint_as_float(w.y & 0xFFFF0000u);
        a4 += __uint_as_float(w.z << 16);
        a5 += __uint_as_float(w.z & 0xFFFF0000u);
        a6 += __uint_as_float(w.w << 16);
        a7 += __uint_as_float(w.w & 0xFFFF0000u);
    }
#define RED8(o)                                                      \
    a0 += __shfl_xor(a0, o, 64); a1 += __shfl_xor(a1, o, 64);        \
    a2 += __shfl_xor(a2, o, 64); a3 += __shfl_xor(a3, o, 64);        \
    a4 += __shfl_xor(a4, o, 64); a5 += __shfl_xor(a5, o, 64);        \
    a6 += __shfl_xor(a6, o, 64); a7 += __shfl_xor(a7, o, 64);
    RED8(8) RED8(16) RED8(32)
#undef RED8
    if (g == 0) {
        float inv = 1.0f / fmaxf((float)(re - rs), 1.0f);
        float4 lo, hi;
        lo.x = a0 * inv; lo.y = a1 * inv; lo.z = a2 * inv; lo.w = a3 * inv;
        hi.x = a4 * inv; hi.y = a5 * inv; hi.z = a6 * inv; hi.w = a7 * inv;
        float4* mp = (float4*)(mean + (long long)node * D + q * 8);
        mp[0] = lo;
        mp[1] = hi;
    }
}

// ---------------- fused dual-linear (+bias, relu), register-tiled ----------------
// also emits bf16 copy of the output for the next layer's gather (outb != nullptr)
__global__ __launch_bounds__(256) void sage_linear_kernel(
    const float* __restrict__ mean, const float* __restrict__ x,
    const float* __restrict__ Wl, const float* __restrict__ bl,
    const float* __restrict__ Wr,
    float* __restrict__ out, unsigned short* __restrict__ outb,
    int nNodes, int doRelu) {
    __shared__ float sWl[D][D];
    __shared__ float sWr[D][D];
    __shared__ float sbl[D];
    __shared__ float sm[TN][D + 1];
    __shared__ float sx[TN][D + 1];

    int t = threadIdx.x;
    for (int i = t; i < D * D; i += 256) {
        int j = i >> 6, k = i & 63;
        sWl[k][j] = Wl[i];
        sWr[k][j] = Wr[i];
    }
    if (t < D) sbl[t] = bl[t];

    int n0 = blockIdx.x * TN;
    for (int i = t; i < TN * D / 4; i += 256) {
        int n = i >> 4;
        int c4 = i & 15;
        int node = n0 + n;
        float4 a, b;
        if (node < nNodes) {
            a = ((const float4*)mean)[(long long)node * 16 + c4];
            b = ((const float4*)x)[(long long)node * 16 + c4];
        } else {
            a = make_float4(0.f, 0.f, 0.f, 0.f);
            b = a;
        }
        sm[n][c4 * 4 + 0] = a.x; sm[n][c4 * 4 + 1] = a.y;
        sm[n][c4 * 4 + 2] = a.z; sm[n][c4 * 4 + 3] = a.w;
        sx[n][c4 * 4 + 0] = b.x; sx[n][c4 * 4 + 1] = b.y;
        sx[n][c4 * 4 + 2] = b.z; sx[n][c4 * 4 + 3] = b.w;
    }
    __syncthreads();

    int jq = t & 15;
    int nb = t >> 4;
    int j0 = jq * 4;
    float acc[4][4];
#pragma unroll
    for (int i = 0; i < 4; ++i)
#pragma unroll
        for (int jj = 0; jj < 4; ++jj) acc[i][jj] = 0.f;

#pragma unroll 4
    for (int k = 0; k < D; ++k) {
        float4 wl = *(const float4*)&sWl[k][j0];
        float4 wr = *(const float4*)&sWr[k][j0];
#pragma unroll
        for (int i = 0; i < 4; ++i) {
            float am = sm[nb * 4 + i][k];
            float av = sx[nb * 4 + i][k];
            acc[i][0] += am * wl.x + av * wr.x;
            acc[i][1] += am * wl.y + av * wr.y;
            acc[i][2] += am * wl.z + av * wr.z;
            acc[i][3] += am * wl.w + av * wr.w;
        }
    }

    float4 bias = *(const float4*)&sbl[j0];
#pragma unroll
    for (int i = 0; i < 4; ++i) {
        int node = n0 + nb * 4 + i;
        if (node >= nNodes) continue;
        float4 o;
        o.x = acc[i][0] + bias.x;
        o.y = acc[i][1] + bias.y;
        o.z = acc[i][2] + bias.z;
        o.w = acc[i][3] + bias.w;
        if (doRelu) {
            o.x = fmaxf(o.x, 0.f); o.y = fmaxf(o.y, 0.f);
            o.z = fmaxf(o.z, 0.f); o.w = fmaxf(o.w, 0.f);
        }
        ((float4*)out)[(long long)node * 16 + jq] = o;
        if (outb) {
            ushort4 ob;
            ob.x = f2bf(o.x); ob.y = f2bf(o.y); ob.z = f2bf(o.z); ob.w = f2bf(o.w);
            ((ushort4*)outb)[(long long)node * 16 + jq] = ob;
        }
    }
}

extern "C" void kernel_launch(void* const* d_in, const int* in_sizes, int n_in,
                              void* d_out, int out_size, void* d_ws, size_t ws_size,
                              hipStream_t stream) {
    const float* x   = (const float*)d_in[0];
    const int*   src = (const int*)d_in[1];
    const int*   dst = (const int*)d_in[2];
    const float* Wl0 = (const float*)d_in[3];
    const float* bl0 = (const float*)d_in[4];
    const float* Wr0 = (const float*)d_in[5];
    const float* Wl1 = (const float*)d_in[6];
    const float* bl1 = (const float*)d_in[7];
    const float* Wr1 = (const float*)d_in[8];
    const float* Wl2 = (const float*)d_in[9];
    const float* bl2 = (const float*)d_in[10];
    const float* Wr2 = (const float*)d_in[11];
    float* out = (float*)d_out;

    const size_t featBytes = (size_t)NN * D * sizeof(float);  // 25.6 MB
    char* ws = (char*)d_ws;
    int* bucket_cnt = (int*)(ws);
    int* bucket_off = (int*)(ws + (16 << 10));
    int* bucket_cur = (int*)(ws + (32 << 10));
    int* bsums      = (int*)(ws + (48 << 10));
    int* counts     = (int*)(ws + (1 << 20));
    int* rowptr     = (int*)(ws + (1 << 20) + (512 << 10));
    int* esrc       = (int*)(ws + (2 << 20));        // NE (6.4 MB)
    char* big = ws + (9 << 20);
    float* mean = (float*)big;                        // 25.6 MB
    unsigned* packed = (unsigned*)big;                // aliases mean (dead until agg)
    float* h1 = (float*)(big + featBytes);
    float* h2 = (float*)(big + 2 * featBytes);
    unsigned short* xb = (unsigned short*)(big + 3 * featBytes);  // 12.8 MB bf16 gather table

    // ---- CSR build ----
    hipMemsetAsync(bucket_cnt, 0, (size_t)NBUCK * sizeof(int), stream);
    p0_bucket_hist<<<P1_BLOCKS, 256, 0, stream>>>(dst, bucket_cnt, NE);
    bucket_scan<<<1, 512, 0, stream>>>(bucket_cnt, bucket_off, bucket_cur);
    p1_partition<<<P1_BLOCKS, 256, 0, stream>>>(src, dst, bucket_cur, packed, NE);
    p2a_hist<<<NBUCK, 256, 0, stream>>>(packed, bucket_off, counts, NN);
    scan_blocksum<<<SCAN_NB, SCAN_B, 0, stream>>>(counts, bsums, NN);
    scan_bsums<<<1, 512, 0, stream>>>(bsums, SCAN_NB, rowptr, NN);
    scan_final<<<SCAN_NB, SCAN_B, 0, stream>>>(counts, bsums, rowptr, NN);
    p2b_place<<<NBUCK, 256, 0, stream>>>(packed, bucket_off, esrc);

    // bf16 gather table for layer 0
    f2bf_kernel<<<(NN * 16 + 255) / 256, 256, 0, stream>>>(x, xb, NN * 16);

    const int aggGrid = (NN * 64 + 255) / 256;
    const int linGrid = (NN + TN - 1) / TN;

    // layer 0
    aggregate_bf16<<<aggGrid, 256, 0, stream>>>(xb, rowptr, esrc, mean, NN);
    sage_linear_kernel<<<linGrid, 256, 0, stream>>>(mean, x, Wl0, bl0, Wr0, h1, xb, NN, 1);

    // layer 1 (xb now holds bf16(h1))
    aggregate_bf16<<<aggGrid, 256, 0, stream>>>(xb, rowptr, esrc, mean, NN);
    sage_linear_kernel<<<linGrid, 256, 0, stream>>>(mean, h1, Wl1, bl1, Wr1, h2, xb, NN, 1);

    // layer 2 (xb now holds bf16(h2))
    aggregate_bf16<<<aggGrid, 256, 0, stream>>>(xb, rowptr, esrc, mean, NN);
    sage_linear_kernel<<<linGrid, 256, 0, stream>>>(mean, h2, Wl2, bl2, Wr2, out, nullptr, NN, 0);
}

// Round 6
// 264.784 us; speedup vs baseline: 17.0108x; 1.4295x over previous
//
#include <hip/hip_runtime.h>

#define NN 100000
#define NE 1600000
#define D 64
#define SCAN_B 256
#define SCAN_NB ((NN + SCAN_B - 1) / SCAN_B)  // 391

#define NBUCK ((NN + 255) / 256)              // 391 buckets of 256 nodes
#define EPB 4096                               // edges per partition block
#define P1_BLOCKS ((NE + EPB - 1) / EPB)       // 391
#define BCAP 6144                              // max edges per bucket

typedef __attribute__((ext_vector_type(8))) short bfrag;   // 8 bf16 = 4 VGPR
typedef __attribute__((ext_vector_type(4))) float f4acc;   // 4 fp32 acc

__device__ __forceinline__ unsigned short f2bf(float f) {
    unsigned u = __float_as_uint(f);
    u = (u + 0x7FFFu + ((u >> 16) & 1u)) >> 16;  // RNE
    return (unsigned short)u;
}

// ---------------- CSR build: bucketed counting sort ----------------
__global__ __launch_bounds__(256) void p0_bucket_hist(const int* __restrict__ dst,
                                                      int* __restrict__ bucket_cnt, int nE) {
    __shared__ int h[NBUCK];
    int t = threadIdx.x;
    for (int i = t; i < NBUCK; i += 256) h[i] = 0;
    __syncthreads();
    int base = blockIdx.x * EPB;
    for (int i = t; i < EPB; i += 256) {
        int e = base + i;
        if (e < nE) atomicAdd(&h[dst[e] >> 8], 1);
    }
    __syncthreads();
    for (int i = t; i < NBUCK; i += 256)
        if (h[i]) atomicAdd(&bucket_cnt[i], h[i]);
}

__global__ __launch_bounds__(512) void bucket_scan(const int* __restrict__ bucket_cnt,
                                                   int* __restrict__ bucket_off,
                                                   int* __restrict__ bucket_cur) {
    __shared__ int s[512];
    int t = threadIdx.x;
    int v = (t < NBUCK) ? bucket_cnt[t] : 0;
    s[t] = v;
    __syncthreads();
    for (int off = 1; off < 512; off <<= 1) {
        int u = (t >= off) ? s[t - off] : 0;
        __syncthreads();
        s[t] += u;
        __syncthreads();
    }
    if (t < NBUCK) { bucket_off[t] = s[t] - v; bucket_cur[t] = s[t] - v; }
    if (t == NBUCK - 1) bucket_off[NBUCK] = s[t];
}

__global__ __launch_bounds__(256) void p1_partition(const int* __restrict__ src,
                                                    const int* __restrict__ dst,
                                                    int* __restrict__ bucket_cur,
                                                    unsigned* __restrict__ packed, int nE) {
    __shared__ int h[NBUCK];
    int t = threadIdx.x;
    for (int i = t; i < NBUCK; i += 256) h[i] = 0;
    __syncthreads();
    int base = blockIdx.x * EPB;
    for (int i = t; i < EPB; i += 256) {
        int e = base + i;
        if (e < nE) atomicAdd(&h[dst[e] >> 8], 1);
    }
    __syncthreads();
    for (int i = t; i < NBUCK; i += 256) {
        int c = h[i];
        h[i] = c ? atomicAdd(&bucket_cur[i], c) : 0;
    }
    __syncthreads();
    for (int i = t; i < EPB; i += 256) {
        int e = base + i;
        if (e < nE) {
            int d = dst[e];
            int pos = atomicAdd(&h[d >> 8], 1);
            packed[pos] = ((unsigned)(d & 255) << 24) | (unsigned)src[e];
        }
    }
}

__global__ __launch_bounds__(256) void p2a_hist(const unsigned* __restrict__ packed,
                                                const int* __restrict__ bucket_off,
                                                int* __restrict__ counts, int nNodes) {
    __shared__ int h[256];
    int b = blockIdx.x, t = threadIdx.x;
    h[t] = 0;
    __syncthreads();
    int lo = bucket_off[b], hi = bucket_off[b + 1];
    for (int i = lo + t; i < hi; i += 256) atomicAdd(&h[packed[i] >> 24], 1);
    __syncthreads();
    int node = b * 256 + t;
    if (node < nNodes) counts[node] = h[t];
}

__global__ __launch_bounds__(256) void p2b_place(const unsigned* __restrict__ packed,
                                                 const int* __restrict__ bucket_off,
                                                 int* __restrict__ esrc) {
    __shared__ int h[256];
    __shared__ int cur[256];
    __shared__ int sl[BCAP];
    int b = blockIdx.x, t = threadIdx.x;
    h[t] = 0;
    __syncthreads();
    int lo = bucket_off[b], hi = bucket_off[b + 1];
    int cnt = hi - lo;
    for (int i = lo + t; i < hi; i += 256) atomicAdd(&h[packed[i] >> 24], 1);
    __syncthreads();
    int v = h[t];
    for (int off = 1; off < 256; off <<= 1) {
        int u = (t >= off) ? h[t - off] : 0;
        __syncthreads();
        h[t] += u;
        __syncthreads();
    }
    cur[t] = h[t] - v;
    __syncthreads();
    for (int i = lo + t; i < hi; i += 256) {
        unsigned p = packed[i];
        int pos = atomicAdd(&cur[p >> 24], 1);
        if (pos < BCAP) sl[pos] = (int)(p & 0xFFFFFFu);
    }
    __syncthreads();
    for (int i = t; i < cnt; i += 256) esrc[lo + i] = sl[i];
}

// ---------------- node-count scan (rowptr) ----------------
__global__ __launch_bounds__(SCAN_B) void scan_blocksum(const int* __restrict__ counts,
                                                        int* __restrict__ bsums, int n) {
    __shared__ int red[SCAN_B];
    int t = threadIdx.x;
    int i = blockIdx.x * SCAN_B + t;
    red[t] = (i < n) ? counts[i] : 0;
    __syncthreads();
    for (int off = SCAN_B / 2; off > 0; off >>= 1) {
        if (t < off) red[t] += red[t + off];
        __syncthreads();
    }
    if (t == 0) bsums[blockIdx.x] = red[0];
}

__global__ __launch_bounds__(512) void scan_bsums(int* __restrict__ bsums, int nb,
                                                  int* __restrict__ rowptr, int n) {
    __shared__ int s[512];
    int t = threadIdx.x;
    int v = (t < nb) ? bsums[t] : 0;
    s[t] = v;
    __syncthreads();
    for (int off = 1; off < 512; off <<= 1) {
        int u = (t >= off) ? s[t - off] : 0;
        __syncthreads();
        s[t] += u;
        __syncthreads();
    }
    if (t < nb) bsums[t] = s[t] - v;
    if (t == nb - 1) rowptr[n] = s[t];
}

__global__ __launch_bounds__(SCAN_B) void scan_final(const int* __restrict__ counts,
                                                     const int* __restrict__ bsums,
                                                     int* __restrict__ rowptr, int n) {
    __shared__ int s[SCAN_B];
    int t = threadIdx.x;
    int i = blockIdx.x * SCAN_B + t;
    int v = (i < n) ? counts[i] : 0;
    s[t] = v;
    __syncthreads();
    for (int off = 1; off < SCAN_B; off <<= 1) {
        int u = (t >= off) ? s[t - off] : 0;
        __syncthreads();
        s[t] += u;
        __syncthreads();
    }
    if (i < n) rowptr[i] = s[t] - v + bsums[blockIdx.x];
}

// ---------------- fp32 -> bf16 table convert (x only) ----------------
__global__ __launch_bounds__(256) void f2bf_kernel(const float* __restrict__ in,
                                                   unsigned short* __restrict__ out, int n4) {
    int i = blockIdx.x * 256 + threadIdx.x;
    if (i < n4) {
        float4 v = ((const float4*)in)[i];
        ushort4 o;
        o.x = f2bf(v.x); o.y = f2bf(v.y); o.z = f2bf(v.z); o.w = f2bf(v.w);
        ((ushort4*)out)[i] = o;
    }
}

// ---------------- weight prep: Wcat[layer][n][k] bf16, k = [Wl | Wr] ----------------
__global__ __launch_bounds__(256) void wprep_kernel(
    const float* __restrict__ Wl0, const float* __restrict__ Wr0,
    const float* __restrict__ Wl1, const float* __restrict__ Wr1,
    const float* __restrict__ Wl2, const float* __restrict__ Wr2,
    unsigned short* __restrict__ wcat) {
    int i = blockIdx.x * 256 + threadIdx.x;  // < 3*64*128
    if (i >= 3 * 64 * 128) return;
    int layer = i >> 13;
    int rem = i & 8191;
    int n = rem >> 7;
    int k = rem & 127;
    const float* W;
    if (layer == 0) W = (k < 64) ? Wl0 : Wr0;
    else if (layer == 1) W = (k < 64) ? Wl1 : Wr1;
    else W = (k < 64) ? Wl2 : Wr2;
    wcat[i] = f2bf(W[n * 64 + (k & 63)]);
}

// ---------------- pull-mode mean aggregation (bf16 gather, fp32 accum, bf16 out) ----------------
__global__ __launch_bounds__(256) void aggregate_bf16(const unsigned short* __restrict__ xb,
                                                      const int* __restrict__ rowptr,
                                                      const int* __restrict__ esrc,
                                                      unsigned short* __restrict__ meanb,
                                                      int nNodes) {
    int node = (blockIdx.x * 256 + threadIdx.x) >> 6;
    if (node >= nNodes) return;
    int lane = threadIdx.x & 63;
    int g = lane >> 3;  // edge slot 0..7
    int q = lane & 7;   // channel group: channels 8q..8q+7
    int rs = rowptr[node];
    int re = rowptr[node + 1];
    float a0 = 0, a1 = 0, a2 = 0, a3 = 0, a4 = 0, a5 = 0, a6 = 0, a7 = 0;
    for (int i = rs + g; i < re; i += 8) {
        int s = esrc[i];
        uint4 w = ((const uint4*)xb)[s * 8 + q];
        a0 += __uint_as_float(w.x << 16);
        a1 += __uint_as_float(w.x & 0xFFFF0000u);
        a2 += __uint_as_float(w.y << 16);
        a3 += __uint_as_float(w.y & 0xFFFF0000u);
        a4 += __uint_as_float(w.z << 16);
        a5 += __uint_as_float(w.z & 0xFFFF0000u);
        a6 += __uint_as_float(w.w << 16);
        a7 += __uint_as_float(w.w & 0xFFFF0000u);
    }
#define RED8(o)                                                      \
    a0 += __shfl_xor(a0, o, 64); a1 += __shfl_xor(a1, o, 64);        \
    a2 += __shfl_xor(a2, o, 64); a3 += __shfl_xor(a3, o, 64);        \
    a4 += __shfl_xor(a4, o, 64); a5 += __shfl_xor(a5, o, 64);        \
    a6 += __shfl_xor(a6, o, 64); a7 += __shfl_xor(a7, o, 64);
    RED8(8) RED8(16) RED8(32)
#undef RED8
    if (g == 0) {
        float inv = 1.0f / fmaxf((float)(re - rs), 1.0f);
        uint4 o;
        o.x = (unsigned)f2bf(a0 * inv) | ((unsigned)f2bf(a1 * inv) << 16);
        o.y = (unsigned)f2bf(a2 * inv) | ((unsigned)f2bf(a3 * inv) << 16);
        o.z = (unsigned)f2bf(a4 * inv) | ((unsigned)f2bf(a5 * inv) << 16);
        o.w = (unsigned)f2bf(a6 * inv) | ((unsigned)f2bf(a7 * inv) << 16);
        ((uint4*)meanb)[node * 8 + q] = o;
    }
}

// ---------------- MFMA dual-linear: out = [meanb|rootb] . Wcat^T + bl ----------------
// block = 4 waves; wave w owns output cols w*16..w*16+15; block owns 64 rows.
// B (weights) in registers; A-frags straight from global (L1-shared across waves).
__global__ __launch_bounds__(256) void sage_linear_mfma(
    const unsigned short* __restrict__ meanb,
    const unsigned short* __restrict__ rootb,
    const unsigned short* __restrict__ wcat,  // [64][128] bf16, this layer
    const float* __restrict__ bl,
    float* __restrict__ outF,                 // may be null
    unsigned short* __restrict__ outB,        // may be null
    int nNodes, int doRelu) {
    int t = threadIdx.x;
    int w = t >> 6;
    int l = t & 63;
    int lr = l & 15;   // A row-in-tile / B col / C col
    int lk = l >> 4;   // k-group

    const bfrag* wB = (const bfrag*)wcat;  // 16 frags per 128-k row
    int n = w * 16 + lr;                   // output channel
    bfrag b0 = wB[n * 16 + 0 * 4 + lk];
    bfrag b1 = wB[n * 16 + 1 * 4 + lk];
    bfrag b2 = wB[n * 16 + 2 * 4 + lk];
    bfrag b3 = wB[n * 16 + 3 * 4 + lk];
    float bias = bl[n];

    int base = blockIdx.x * 64;
#pragma unroll
    for (int rt = 0; rt < 4; ++rt) {
        int row0 = base + rt * 16;
        const bfrag* mr = (const bfrag*)(meanb + (size_t)(row0 + lr) * D);
        const bfrag* xr = (const bfrag*)(rootb + (size_t)(row0 + lr) * D);
        bfrag a0 = mr[lk];
        bfrag a1 = mr[4 + lk];
        bfrag a2 = xr[lk];
        bfrag a3 = xr[4 + lk];
        f4acc acc = {0.f, 0.f, 0.f, 0.f};
        acc = __builtin_amdgcn_mfma_f32_16x16x32_bf16(a0, b0, acc, 0, 0, 0);
        acc = __builtin_amdgcn_mfma_f32_16x16x32_bf16(a1, b1, acc, 0, 0, 0);
        acc = __builtin_amdgcn_mfma_f32_16x16x32_bf16(a2, b2, acc, 0, 0, 0);
        acc = __builtin_amdgcn_mfma_f32_16x16x32_bf16(a3, b3, acc, 0, 0, 0);
#pragma unroll
        for (int r = 0; r < 4; ++r) {
            int row = row0 + lk * 4 + r;
            if (row >= nNodes) continue;
            float v = acc[r] + bias;
            if (doRelu) v = fmaxf(v, 0.f);
            if (outF) outF[(size_t)row * D + n] = v;
            if (outB) outB[(size_t)row * D + n] = f2bf(v);
        }
    }
}

extern "C" void kernel_launch(void* const* d_in, const int* in_sizes, int n_in,
                              void* d_out, int out_size, void* d_ws, size_t ws_size,
                              hipStream_t stream) {
    const float* x   = (const float*)d_in[0];
    const int*   src = (const int*)d_in[1];
    const int*   dst = (const int*)d_in[2];
    const float* Wl0 = (const float*)d_in[3];
    const float* bl0 = (const float*)d_in[4];
    const float* Wr0 = (const float*)d_in[5];
    const float* Wl1 = (const float*)d_in[6];
    const float* bl1 = (const float*)d_in[7];
    const float* Wr1 = (const float*)d_in[8];
    const float* Wl2 = (const float*)d_in[9];
    const float* bl2 = (const float*)d_in[10];
    const float* Wr2 = (const float*)d_in[11];
    float* out = (float*)d_out;

    const size_t bfeatBytes = (size_t)NN * D * 2;  // 12.8 MB (bf16 table)
    char* ws = (char*)d_ws;
    int* bucket_cnt = (int*)(ws);
    int* bucket_off = (int*)(ws + (16 << 10));
    int* bucket_cur = (int*)(ws + (32 << 10));
    int* bsums      = (int*)(ws + (48 << 10));
    unsigned short* wcat = (unsigned short*)(ws + (128 << 10));  // 48 KB
    int* counts     = (int*)(ws + (1 << 20));
    int* rowptr     = (int*)(ws + (1 << 20) + (512 << 10));
    int* esrc       = (int*)(ws + (2 << 20));        // NE (6.4 MB)
    char* big = ws + (9 << 20);
    unsigned short* meanb = (unsigned short*)big;                      // 12.8 MB
    unsigned* packed = (unsigned*)big;                                  // aliases meanb (dead by agg time)
    unsigned short* xb  = (unsigned short*)(big + bfeatBytes);          // 12.8 MB
    unsigned short* hbA = (unsigned short*)(big + 2 * bfeatBytes);      // 12.8 MB
    unsigned short* hbB = (unsigned short*)(big + 3 * bfeatBytes);      // 12.8 MB

    // ---- CSR build ----
    hipMemsetAsync(bucket_cnt, 0, (size_t)NBUCK * sizeof(int), stream);
    p0_bucket_hist<<<P1_BLOCKS, 256, 0, stream>>>(dst, bucket_cnt, NE);
    bucket_scan<<<1, 512, 0, stream>>>(bucket_cnt, bucket_off, bucket_cur);
    p1_partition<<<P1_BLOCKS, 256, 0, stream>>>(src, dst, bucket_cur, packed, NE);
    p2a_hist<<<NBUCK, 256, 0, stream>>>(packed, bucket_off, counts, NN);
    scan_blocksum<<<SCAN_NB, SCAN_B, 0, stream>>>(counts, bsums, NN);
    scan_bsums<<<1, 512, 0, stream>>>(bsums, SCAN_NB, rowptr, NN);
    scan_final<<<SCAN_NB, SCAN_B, 0, stream>>>(counts, bsums, rowptr, NN);
    p2b_place<<<NBUCK, 256, 0, stream>>>(packed, bucket_off, esrc);

    // ---- tables ----
    f2bf_kernel<<<(NN * 16 + 255) / 256, 256, 0, stream>>>(x, xb, NN * 16);
    wprep_kernel<<<(3 * 64 * 128 + 255) / 256, 256, 0, stream>>>(Wl0, Wr0, Wl1, Wr1, Wl2, Wr2, wcat);

    const int aggGrid = (NN * 64 + 255) / 256;  // one wave per node
    const int linGrid = (NN + 63) / 64;

    // layer 0
    aggregate_bf16<<<aggGrid, 256, 0, stream>>>(xb, rowptr, esrc, meanb, NN);
    sage_linear_mfma<<<linGrid, 256, 0, stream>>>(meanb, xb, wcat, bl0, nullptr, hbA, NN, 1);

    // layer 1
    aggregate_bf16<<<aggGrid, 256, 0, stream>>>(hbA, rowptr, esrc, meanb, NN);
    sage_linear_mfma<<<linGrid, 256, 0, stream>>>(meanb, hbA, wcat + 8192, bl1, nullptr, hbB, NN, 1);

    // layer 2
    aggregate_bf16<<<aggGrid, 256, 0, stream>>>(hbB, rowptr, esrc, meanb, NN);
    sage_linear_mfma<<<linGrid, 256, 0, stream>>>(meanb, hbB, wcat + 16384, bl2, out, nullptr, NN, 0);
}

// Round 7
// 231.541 us; speedup vs baseline: 19.4531x; 1.1436x over previous
//
#include <hip/hip_runtime.h>

#define NN 100000
#define NE 1600000
#define D 64

#define NBUCK ((NN + 255) / 256)              // 391 buckets of 256 nodes
#define EPB 4096                               // edges per partition block
#define P1_BLOCKS ((NE + EPB - 1) / EPB)       // 391
#define BCAP 6144                              // max edges per bucket

typedef __attribute__((ext_vector_type(8))) short bfrag;   // 8 bf16 = 4 VGPR
typedef __attribute__((ext_vector_type(4))) float f4acc;   // 4 fp32 acc

__device__ __forceinline__ unsigned short f2bf(float f) {
    unsigned u = __float_as_uint(f);
    u = (u + 0x7FFFu + ((u >> 16) & 1u)) >> 16;  // RNE
    return (unsigned short)u;
}

// ---------------- CSR build: bucketed counting sort ----------------
__global__ __launch_bounds__(256) void p0_bucket_hist(const int* __restrict__ dst,
                                                      int* __restrict__ bucket_cnt, int nE) {
    __shared__ int h[NBUCK];
    int t = threadIdx.x;
    for (int i = t; i < NBUCK; i += 256) h[i] = 0;
    __syncthreads();
    int base = blockIdx.x * EPB;
    for (int i = t; i < EPB; i += 256) {
        int e = base + i;
        if (e < nE) atomicAdd(&h[dst[e] >> 8], 1);
    }
    __syncthreads();
    for (int i = t; i < NBUCK; i += 256)
        if (h[i]) atomicAdd(&bucket_cnt[i], h[i]);
}

__global__ __launch_bounds__(512) void bucket_scan(const int* __restrict__ bucket_cnt,
                                                   int* __restrict__ bucket_off,
                                                   int* __restrict__ bucket_cur,
                                                   int* __restrict__ rowptr) {
    __shared__ int s[512];
    int t = threadIdx.x;
    int v = (t < NBUCK) ? bucket_cnt[t] : 0;
    s[t] = v;
    __syncthreads();
    for (int off = 1; off < 512; off <<= 1) {
        int u = (t >= off) ? s[t - off] : 0;
        __syncthreads();
        s[t] += u;
        __syncthreads();
    }
    if (t < NBUCK) { bucket_off[t] = s[t] - v; bucket_cur[t] = s[t] - v; }
    if (t == NBUCK - 1) { bucket_off[NBUCK] = s[t]; rowptr[NN] = s[t]; }
}

__global__ __launch_bounds__(256) void p1_partition(const int* __restrict__ src,
                                                    const int* __restrict__ dst,
                                                    int* __restrict__ bucket_cur,
                                                    unsigned* __restrict__ packed, int nE) {
    __shared__ int h[NBUCK];
    int t = threadIdx.x;
    for (int i = t; i < NBUCK; i += 256) h[i] = 0;
    __syncthreads();
    int base = blockIdx.x * EPB;
    for (int i = t; i < EPB; i += 256) {
        int e = base + i;
        if (e < nE) atomicAdd(&h[dst[e] >> 8], 1);
    }
    __syncthreads();
    for (int i = t; i < NBUCK; i += 256) {
        int c = h[i];
        h[i] = c ? atomicAdd(&bucket_cur[i], c) : 0;
    }
    __syncthreads();
    for (int i = t; i < EPB; i += 256) {
        int e = base + i;
        if (e < nE) {
            int d = dst[e];
            int pos = atomicAdd(&h[d >> 8], 1);
            packed[pos] = ((unsigned)(d & 255) << 24) | (unsigned)src[e];
        }
    }
}

// p2b: per-bucket histogram + local scan -> rowptr write; in-LDS counting sort -> esrc
__global__ __launch_bounds__(256) void p2b_place(const unsigned* __restrict__ packed,
                                                 const int* __restrict__ bucket_off,
                                                 int* __restrict__ rowptr,
                                                 int* __restrict__ esrc, int nNodes) {
    __shared__ int h[256];
    __shared__ int cur[256];
    __shared__ int sl[BCAP];
    int b = blockIdx.x, t = threadIdx.x;
    h[t] = 0;
    __syncthreads();
    int lo = bucket_off[b], hi = bucket_off[b + 1];
    int cnt = hi - lo;
    for (int i = lo + t; i < hi; i += 256) atomicAdd(&h[packed[i] >> 24], 1);
    __syncthreads();
    int v = h[t];
    for (int off = 1; off < 256; off <<= 1) {
        int u = (t >= off) ? h[t - off] : 0;
        __syncthreads();
        h[t] += u;
        __syncthreads();
    }
    int excl = h[t] - v;
    cur[t] = excl;
    int node = b * 256 + t;
    if (node < nNodes) rowptr[node] = lo + excl;
    __syncthreads();
    for (int i = lo + t; i < hi; i += 256) {
        unsigned p = packed[i];
        int pos = atomicAdd(&cur[p >> 24], 1);
        if (pos < BCAP) sl[pos] = (int)(p & 0xFFFFFFu);
    }
    __syncthreads();
    for (int i = t; i < cnt; i += 256) esrc[lo + i] = sl[i];
}

// ---------------- fp32 -> bf16 table convert (x only) ----------------
__global__ __launch_bounds__(256) void f2bf_kernel(const float* __restrict__ in,
                                                   unsigned short* __restrict__ out, int n4) {
    int i = blockIdx.x * 256 + threadIdx.x;
    if (i < n4) {
        float4 v = ((const float4*)in)[i];
        ushort4 o;
        o.x = f2bf(v.x); o.y = f2bf(v.y); o.z = f2bf(v.z); o.w = f2bf(v.w);
        ((ushort4*)out)[i] = o;
    }
}

// ---------------- weight prep: Wcat[layer][n][k] bf16, k = [Wl | Wr] ----------------
__global__ __launch_bounds__(256) void wprep_kernel(
    const float* __restrict__ Wl0, const float* __restrict__ Wr0,
    const float* __restrict__ Wl1, const float* __restrict__ Wr1,
    const float* __restrict__ Wl2, const float* __restrict__ Wr2,
    unsigned short* __restrict__ wcat) {
    int i = blockIdx.x * 256 + threadIdx.x;  // < 3*64*128
    if (i >= 3 * 64 * 128) return;
    int layer = i >> 13;
    int rem = i & 8191;
    int n = rem >> 7;
    int k = rem & 127;
    const float* W;
    if (layer == 0) W = (k < 64) ? Wl0 : Wr0;
    else if (layer == 1) W = (k < 64) ? Wl1 : Wr1;
    else W = (k < 64) ? Wl2 : Wr2;
    wcat[i] = f2bf(W[n * 64 + (k & 63)]);
}

// ---------------- pull-mode mean aggregation ----------------
// 8 lanes per node (8 nodes/wave). Batch 8 esrc indices per group via one
// coalesced load, shfl-broadcast each, 8 independent 16B gathers in flight.
// No reduction tail: each lane owns channels 8q..8q+7.
__global__ __launch_bounds__(256) void aggregate_bf16(const unsigned short* __restrict__ xb,
                                                      const int* __restrict__ rowptr,
                                                      const int* __restrict__ esrc,
                                                      unsigned short* __restrict__ meanb,
                                                      int nNodes) {
    int node = (blockIdx.x * 256 + threadIdx.x) >> 3;
    if (node >= nNodes) return;
    int q = threadIdx.x & 7;        // channel octet
    int lane = threadIdx.x & 63;
    int gbase = lane & 56;          // group base lane within wave
    int rs = rowptr[node];
    int re = rowptr[node + 1];
    float a0 = 0, a1 = 0, a2 = 0, a3 = 0, a4 = 0, a5 = 0, a6 = 0, a7 = 0;
    for (int i = rs; i < re; i += 8) {
        int ei = i + q;
        int mySrc = (ei < re) ? esrc[ei] : -1;
#pragma unroll
        for (int j = 0; j < 8; ++j) {
            int s = __shfl(mySrc, gbase + j, 64);
            if (s < 0) break;  // uniform within the 8-lane group
            uint4 w = ((const uint4*)xb)[s * 8 + q];
            a0 += __uint_as_float(w.x << 16);
            a1 += __uint_as_float(w.x & 0xFFFF0000u);
            a2 += __uint_as_float(w.y << 16);
            a3 += __uint_as_float(w.y & 0xFFFF0000u);
            a4 += __uint_as_float(w.z << 16);
            a5 += __uint_as_float(w.z & 0xFFFF0000u);
            a6 += __uint_as_float(w.w << 16);
            a7 += __uint_as_float(w.w & 0xFFFF0000u);
        }
    }
    float inv = 1.0f / fmaxf((float)(re - rs), 1.0f);
    uint4 o;
    o.x = (unsigned)f2bf(a0 * inv) | ((unsigned)f2bf(a1 * inv) << 16);
    o.y = (unsigned)f2bf(a2 * inv) | ((unsigned)f2bf(a3 * inv) << 16);
    o.z = (unsigned)f2bf(a4 * inv) | ((unsigned)f2bf(a5 * inv) << 16);
    o.w = (unsigned)f2bf(a6 * inv) | ((unsigned)f2bf(a7 * inv) << 16);
    ((uint4*)meanb)[node * 8 + q] = o;
}

// ---------------- MFMA dual-linear: out = [meanb|rootb] . Wcat^T + bl ----------------
__global__ __launch_bounds__(256) void sage_linear_mfma(
    const unsigned short* __restrict__ meanb,
    const unsigned short* __restrict__ rootb,
    const unsigned short* __restrict__ wcat,  // [64][128] bf16, this layer
    const float* __restrict__ bl,
    float* __restrict__ outF,                 // may be null
    unsigned short* __restrict__ outB,        // may be null
    int nNodes, int doRelu) {
    int t = threadIdx.x;
    int w = t >> 6;
    int l = t & 63;
    int lr = l & 15;   // A row-in-tile / B col / C col
    int lk = l >> 4;   // k-group

    const bfrag* wB = (const bfrag*)wcat;  // 16 frags per 128-k row
    int n = w * 16 + lr;                   // output channel
    bfrag b0 = wB[n * 16 + 0 * 4 + lk];
    bfrag b1 = wB[n * 16 + 1 * 4 + lk];
    bfrag b2 = wB[n * 16 + 2 * 4 + lk];
    bfrag b3 = wB[n * 16 + 3 * 4 + lk];
    float bias = bl[n];

    int base = blockIdx.x * 64;
#pragma unroll
    for (int rt = 0; rt < 4; ++rt) {
        int row0 = base + rt * 16;
        const bfrag* mr = (const bfrag*)(meanb + (size_t)(row0 + lr) * D);
        const bfrag* xr = (const bfrag*)(rootb + (size_t)(row0 + lr) * D);
        bfrag a0 = mr[lk];
        bfrag a1 = mr[4 + lk];
        bfrag a2 = xr[lk];
        bfrag a3 = xr[4 + lk];
        f4acc acc = {0.f, 0.f, 0.f, 0.f};
        acc = __builtin_amdgcn_mfma_f32_16x16x32_bf16(a0, b0, acc, 0, 0, 0);
        acc = __builtin_amdgcn_mfma_f32_16x16x32_bf16(a1, b1, acc, 0, 0, 0);
        acc = __builtin_amdgcn_mfma_f32_16x16x32_bf16(a2, b2, acc, 0, 0, 0);
        acc = __builtin_amdgcn_mfma_f32_16x16x32_bf16(a3, b3, acc, 0, 0, 0);
#pragma unroll
        for (int r = 0; r < 4; ++r) {
            int row = row0 + lk * 4 + r;
            if (row >= nNodes) continue;
            float v = acc[r] + bias;
            if (doRelu) v = fmaxf(v, 0.f);
            if (outF) outF[(size_t)row * D + n] = v;
            if (outB) outB[(size_t)row * D + n] = f2bf(v);
        }
    }
}

extern "C" void kernel_launch(void* const* d_in, const int* in_sizes, int n_in,
                              void* d_out, int out_size, void* d_ws, size_t ws_size,
                              hipStream_t stream) {
    const float* x   = (const float*)d_in[0];
    const int*   src = (const int*)d_in[1];
    const int*   dst = (const int*)d_in[2];
    const float* Wl0 = (const float*)d_in[3];
    const float* bl0 = (const float*)d_in[4];
    const float* Wr0 = (const float*)d_in[5];
    const float* Wl1 = (const float*)d_in[6];
    const float* bl1 = (const float*)d_in[7];
    const float* Wr1 = (const float*)d_in[8];
    const float* Wl2 = (const float*)d_in[9];
    const float* bl2 = (const float*)d_in[10];
    const float* Wr2 = (const float*)d_in[11];
    float* out = (float*)d_out;

    const size_t bfeatBytes = (size_t)NN * D * 2;  // 12.8 MB (bf16 table)
    char* ws = (char*)d_ws;
    int* bucket_cnt = (int*)(ws);
    int* bucket_off = (int*)(ws + (16 << 10));
    int* bucket_cur = (int*)(ws + (32 << 10));
    unsigned short* wcat = (unsigned short*)(ws + (128 << 10));  // 48 KB
    int* rowptr     = (int*)(ws + (1 << 20));        // NN+1
    int* esrc       = (int*)(ws + (2 << 20));        // NE (6.4 MB)
    char* big = ws + (9 << 20);
    unsigned short* meanb = (unsigned short*)big;                      // 12.8 MB
    unsigned* packed = (unsigned*)big;                                  // aliases meanb (dead by agg time)
    unsigned short* xb  = (unsigned short*)(big + bfeatBytes);          // 12.8 MB
    unsigned short* hbA = (unsigned short*)(big + 2 * bfeatBytes);      // 12.8 MB
    unsigned short* hbB = (unsigned short*)(big + 3 * bfeatBytes);      // 12.8 MB

    // ---- CSR build ----
    hipMemsetAsync(bucket_cnt, 0, (size_t)NBUCK * sizeof(int), stream);
    p0_bucket_hist<<<P1_BLOCKS, 256, 0, stream>>>(dst, bucket_cnt, NE);
    bucket_scan<<<1, 512, 0, stream>>>(bucket_cnt, bucket_off, bucket_cur, rowptr);
    p1_partition<<<P1_BLOCKS, 256, 0, stream>>>(src, dst, bucket_cur, packed, NE);
    p2b_place<<<NBUCK, 256, 0, stream>>>(packed, bucket_off, rowptr, esrc, NN);

    // ---- tables ----
    f2bf_kernel<<<(NN * 16 + 255) / 256, 256, 0, stream>>>(x, xb, NN * 16);
    wprep_kernel<<<(3 * 64 * 128 + 255) / 256, 256, 0, stream>>>(Wl0, Wr0, Wl1, Wr1, Wl2, Wr2, wcat);

    const int aggGrid = (NN * 8 + 255) / 256;   // 8 lanes per node
    const int linGrid = (NN + 63) / 64;

    // layer 0
    aggregate_bf16<<<aggGrid, 256, 0, stream>>>(xb, rowptr, esrc, meanb, NN);
    sage_linear_mfma<<<linGrid, 256, 0, stream>>>(meanb, xb, wcat, bl0, nullptr, hbA, NN, 1);

    // layer 1
    aggregate_bf16<<<aggGrid, 256, 0, stream>>>(hbA, rowptr, esrc, meanb, NN);
    sage_linear_mfma<<<linGrid, 256, 0, stream>>>(meanb, hbA, wcat + 8192, bl1, nullptr, hbB, NN, 1);

    // layer 2
    aggregate_bf16<<<aggGrid, 256, 0, stream>>>(hbB, rowptr, esrc, meanb, NN);
    sage_linear_mfma<<<linGrid, 256, 0, stream>>>(meanb, hbB, wcat + 16384, bl2, out, nullptr, NN, 0);
}

// Round 8
// 230.364 us; speedup vs baseline: 19.5525x; 1.0051x over previous
//
#include <hip/hip_runtime.h>

#define NN 100000
#define NE 1600000
#define D 64

#define NBUCK ((NN + 255) / 256)              // 391 buckets of 256 nodes
#define EPB 4096                               // edges per partition block
#define P1_BLOCKS ((NE + EPB - 1) / EPB)       // 391
#define BCAP 6144                              // max edges per bucket

typedef __attribute__((ext_vector_type(8))) short bfrag;   // 8 bf16 = 4 VGPR
typedef __attribute__((ext_vector_type(4))) float f4acc;   // 4 fp32 acc

__device__ __forceinline__ unsigned short f2bf(float f) {
    unsigned u = __float_as_uint(f);
    u = (u + 0x7FFFu + ((u >> 16) & 1u)) >> 16;  // RNE
    return (unsigned short)u;
}

// ---------------- tiny zero (replaces hipMemsetAsync: rocclr fill = 40us in-graph) ----
__global__ __launch_bounds__(256) void zero_kernel(int* __restrict__ p, int n) {
    int i = blockIdx.x * 256 + threadIdx.x;
    if (i < n) p[i] = 0;
}

// ---------------- CSR build: bucketed counting sort ----------------
__global__ __launch_bounds__(256) void p0_bucket_hist(const int* __restrict__ dst,
                                                      int* __restrict__ bucket_cnt, int nE) {
    __shared__ int h[NBUCK];
    int t = threadIdx.x;
    for (int i = t; i < NBUCK; i += 256) h[i] = 0;
    __syncthreads();
    int base = blockIdx.x * EPB;
    for (int i = t; i < EPB; i += 256) {
        int e = base + i;
        if (e < nE) atomicAdd(&h[dst[e] >> 8], 1);
    }
    __syncthreads();
    for (int i = t; i < NBUCK; i += 256)
        if (h[i]) atomicAdd(&bucket_cnt[i], h[i]);
}

__global__ __launch_bounds__(512) void bucket_scan(const int* __restrict__ bucket_cnt,
                                                   int* __restrict__ bucket_off,
                                                   int* __restrict__ bucket_cur,
                                                   int* __restrict__ rowptr) {
    __shared__ int s[512];
    int t = threadIdx.x;
    int v = (t < NBUCK) ? bucket_cnt[t] : 0;
    s[t] = v;
    __syncthreads();
    for (int off = 1; off < 512; off <<= 1) {
        int u = (t >= off) ? s[t - off] : 0;
        __syncthreads();
        s[t] += u;
        __syncthreads();
    }
    if (t < NBUCK) { bucket_off[t] = s[t] - v; bucket_cur[t] = s[t] - v; }
    if (t == NBUCK - 1) { bucket_off[NBUCK] = s[t]; rowptr[NN] = s[t]; }
}

__global__ __launch_bounds__(256) void p1_partition(const int* __restrict__ src,
                                                    const int* __restrict__ dst,
                                                    int* __restrict__ bucket_cur,
                                                    unsigned* __restrict__ packed, int nE) {
    __shared__ int h[NBUCK];
    int t = threadIdx.x;
    for (int i = t; i < NBUCK; i += 256) h[i] = 0;
    __syncthreads();
    int base = blockIdx.x * EPB;
    for (int i = t; i < EPB; i += 256) {
        int e = base + i;
        if (e < nE) atomicAdd(&h[dst[e] >> 8], 1);
    }
    __syncthreads();
    for (int i = t; i < NBUCK; i += 256) {
        int c = h[i];
        h[i] = c ? atomicAdd(&bucket_cur[i], c) : 0;
    }
    __syncthreads();
    for (int i = t; i < EPB; i += 256) {
        int e = base + i;
        if (e < nE) {
            int d = dst[e];
            int pos = atomicAdd(&h[d >> 8], 1);
            packed[pos] = ((unsigned)(d & 255) << 24) | (unsigned)src[e];
        }
    }
}

// p2b: per-bucket histogram + local scan -> rowptr write; in-LDS counting sort -> esrc
__global__ __launch_bounds__(256) void p2b_place(const unsigned* __restrict__ packed,
                                                 const int* __restrict__ bucket_off,
                                                 int* __restrict__ rowptr,
                                                 int* __restrict__ esrc, int nNodes) {
    __shared__ int h[256];
    __shared__ int cur[256];
    __shared__ int sl[BCAP];
    int b = blockIdx.x, t = threadIdx.x;
    h[t] = 0;
    __syncthreads();
    int lo = bucket_off[b], hi = bucket_off[b + 1];
    int cnt = hi - lo;
    for (int i = lo + t; i < hi; i += 256) atomicAdd(&h[packed[i] >> 24], 1);
    __syncthreads();
    int v = h[t];
    for (int off = 1; off < 256; off <<= 1) {
        int u = (t >= off) ? h[t - off] : 0;
        __syncthreads();
        h[t] += u;
        __syncthreads();
    }
    int excl = h[t] - v;
    cur[t] = excl;
    int node = b * 256 + t;
    if (node < nNodes) rowptr[node] = lo + excl;
    __syncthreads();
    for (int i = lo + t; i < hi; i += 256) {
        unsigned p = packed[i];
        int pos = atomicAdd(&cur[p >> 24], 1);
        if (pos < BCAP) sl[pos] = (int)(p & 0xFFFFFFu);
    }
    __syncthreads();
    for (int i = t; i < cnt; i += 256) esrc[lo + i] = sl[i];
}

// ---------------- fp32 -> bf16 table convert (x only) ----------------
__global__ __launch_bounds__(256) void f2bf_kernel(const float* __restrict__ in,
                                                   unsigned short* __restrict__ out, int n4) {
    int i = blockIdx.x * 256 + threadIdx.x;
    if (i < n4) {
        float4 v = ((const float4*)in)[i];
        ushort4 o;
        o.x = f2bf(v.x); o.y = f2bf(v.y); o.z = f2bf(v.z); o.w = f2bf(v.w);
        ((ushort4*)out)[i] = o;
    }
}

// ---------------- weight prep: Wcat[layer][n][k] bf16, k = [Wl | Wr] ----------------
__global__ __launch_bounds__(256) void wprep_kernel(
    const float* __restrict__ Wl0, const float* __restrict__ Wr0,
    const float* __restrict__ Wl1, const float* __restrict__ Wr1,
    const float* __restrict__ Wl2, const float* __restrict__ Wr2,
    unsigned short* __restrict__ wcat) {
    int i = blockIdx.x * 256 + threadIdx.x;  // < 3*64*128
    if (i >= 3 * 64 * 128) return;
    int layer = i >> 13;
    int rem = i & 8191;
    int n = rem >> 7;
    int k = rem & 127;
    const float* W;
    if (layer == 0) W = (k < 64) ? Wl0 : Wr0;
    else if (layer == 1) W = (k < 64) ? Wl1 : Wr1;
    else W = (k < 64) ? Wl2 : Wr2;
    wcat[i] = f2bf(W[n * 64 + (k & 63)]);
}

// ---------------- pull-mode mean aggregation ----------------
// 8 lanes per node (8 nodes/wave); coalesced index batch + shfl broadcast;
// each lane owns channels 8q..8q+7 end-to-end (no reduce tail).
__global__ __launch_bounds__(256) void aggregate_bf16(const unsigned short* __restrict__ xb,
                                                      const int* __restrict__ rowptr,
                                                      const int* __restrict__ esrc,
                                                      unsigned short* __restrict__ meanb,
                                                      int nNodes) {
    int node = (blockIdx.x * 256 + threadIdx.x) >> 3;
    if (node >= nNodes) return;
    int q = threadIdx.x & 7;        // channel octet
    int lane = threadIdx.x & 63;
    int gbase = lane & 56;          // group base lane within wave
    int rs = rowptr[node];
    int re = rowptr[node + 1];
    float a0 = 0, a1 = 0, a2 = 0, a3 = 0, a4 = 0, a5 = 0, a6 = 0, a7 = 0;
    for (int i = rs; i < re; i += 8) {
        int ei = i + q;
        int mySrc = (ei < re) ? esrc[ei] : -1;
#pragma unroll
        for (int j = 0; j < 8; ++j) {
            int s = __shfl(mySrc, gbase + j, 64);
            if (s < 0) break;  // uniform within the 8-lane group
            uint4 w = ((const uint4*)xb)[s * 8 + q];
            a0 += __uint_as_float(w.x << 16);
            a1 += __uint_as_float(w.x & 0xFFFF0000u);
            a2 += __uint_as_float(w.y << 16);
            a3 += __uint_as_float(w.y & 0xFFFF0000u);
            a4 += __uint_as_float(w.z << 16);
            a5 += __uint_as_float(w.z & 0xFFFF0000u);
            a6 += __uint_as_float(w.w << 16);
            a7 += __uint_as_float(w.w & 0xFFFF0000u);
        }
    }
    float inv = 1.0f / fmaxf((float)(re - rs), 1.0f);
    uint4 o;
    o.x = (unsigned)f2bf(a0 * inv) | ((unsigned)f2bf(a1 * inv) << 16);
    o.y = (unsigned)f2bf(a2 * inv) | ((unsigned)f2bf(a3 * inv) << 16);
    o.z = (unsigned)f2bf(a4 * inv) | ((unsigned)f2bf(a5 * inv) << 16);
    o.w = (unsigned)f2bf(a6 * inv) | ((unsigned)f2bf(a7 * inv) << 16);
    ((uint4*)meanb)[node * 8 + q] = o;
}

// ---------------- MFMA dual-linear: out = [meanb|rootb] . Wcat^T + bl ----------------
__global__ __launch_bounds__(256) void sage_linear_mfma(
    const unsigned short* __restrict__ meanb,
    const unsigned short* __restrict__ rootb,
    const unsigned short* __restrict__ wcat,  // [64][128] bf16, this layer
    const float* __restrict__ bl,
    float* __restrict__ outF,                 // may be null
    unsigned short* __restrict__ outB,        // may be null
    int nNodes, int doRelu) {
    int t = threadIdx.x;
    int w = t >> 6;
    int l = t & 63;
    int lr = l & 15;   // A row-in-tile / B col / C col
    int lk = l >> 4;   // k-group

    const bfrag* wB = (const bfrag*)wcat;  // 16 frags per 128-k row
    int n = w * 16 + lr;                   // output channel
    bfrag b0 = wB[n * 16 + 0 * 4 + lk];
    bfrag b1 = wB[n * 16 + 1 * 4 + lk];
    bfrag b2 = wB[n * 16 + 2 * 4 + lk];
    bfrag b3 = wB[n * 16 + 3 * 4 + lk];
    float bias = bl[n];

    int base = blockIdx.x * 64;
#pragma unroll
    for (int rt = 0; rt < 4; ++rt) {
        int row0 = base + rt * 16;
        const bfrag* mr = (const bfrag*)(meanb + (size_t)(row0 + lr) * D);
        const bfrag* xr = (const bfrag*)(rootb + (size_t)(row0 + lr) * D);
        bfrag a0 = mr[lk];
        bfrag a1 = mr[4 + lk];
        bfrag a2 = xr[lk];
        bfrag a3 = xr[4 + lk];
        f4acc acc = {0.f, 0.f, 0.f, 0.f};
        acc = __builtin_amdgcn_mfma_f32_16x16x32_bf16(a0, b0, acc, 0, 0, 0);
        acc = __builtin_amdgcn_mfma_f32_16x16x32_bf16(a1, b1, acc, 0, 0, 0);
        acc = __builtin_amdgcn_mfma_f32_16x16x32_bf16(a2, b2, acc, 0, 0, 0);
        acc = __builtin_amdgcn_mfma_f32_16x16x32_bf16(a3, b3, acc, 0, 0, 0);
#pragma unroll
        for (int r = 0; r < 4; ++r) {
            int row = row0 + lk * 4 + r;
            if (row >= nNodes) continue;
            float v = acc[r] + bias;
            if (doRelu) v = fmaxf(v, 0.f);
            if (outF) outF[(size_t)row * D + n] = v;
            if (outB) outB[(size_t)row * D + n] = f2bf(v);
        }
    }
}

extern "C" void kernel_launch(void* const* d_in, const int* in_sizes, int n_in,
                              void* d_out, int out_size, void* d_ws, size_t ws_size,
                              hipStream_t stream) {
    const float* x   = (const float*)d_in[0];
    const int*   src = (const int*)d_in[1];
    const int*   dst = (const int*)d_in[2];
    const float* Wl0 = (const float*)d_in[3];
    const float* bl0 = (const float*)d_in[4];
    const float* Wr0 = (const float*)d_in[5];
    const float* Wl1 = (const float*)d_in[6];
    const float* bl1 = (const float*)d_in[7];
    const float* Wr1 = (const float*)d_in[8];
    const float* Wl2 = (const float*)d_in[9];
    const float* bl2 = (const float*)d_in[10];
    const float* Wr2 = (const float*)d_in[11];
    float* out = (float*)d_out;

    const size_t bfeatBytes = (size_t)NN * D * 2;  // 12.8 MB (bf16 table)
    char* ws = (char*)d_ws;
    int* bucket_cnt = (int*)(ws);
    int* bucket_off = (int*)(ws + (16 << 10));
    int* bucket_cur = (int*)(ws + (32 << 10));
    unsigned short* wcat = (unsigned short*)(ws + (128 << 10));  // 48 KB
    int* rowptr     = (int*)(ws + (1 << 20));        // NN+1
    int* esrc       = (int*)(ws + (2 << 20));        // NE (6.4 MB)
    char* big = ws + (9 << 20);
    unsigned short* meanb = (unsigned short*)big;                      // 12.8 MB
    unsigned* packed = (unsigned*)big;                                  // aliases meanb (dead by agg time)
    unsigned short* xb  = (unsigned short*)(big + bfeatBytes);          // 12.8 MB
    unsigned short* hbA = (unsigned short*)(big + 2 * bfeatBytes);      // 12.8 MB
    unsigned short* hbB = (unsigned short*)(big + 3 * bfeatBytes);      // 12.8 MB

    // ---- CSR build ----
    zero_kernel<<<(NBUCK + 255) / 256, 256, 0, stream>>>(bucket_cnt, NBUCK);
    p0_bucket_hist<<<P1_BLOCKS, 256, 0, stream>>>(dst, bucket_cnt, NE);
    bucket_scan<<<1, 512, 0, stream>>>(bucket_cnt, bucket_off, bucket_cur, rowptr);
    p1_partition<<<P1_BLOCKS, 256, 0, stream>>>(src, dst, bucket_cur, packed, NE);
    p2b_place<<<NBUCK, 256, 0, stream>>>(packed, bucket_off, rowptr, esrc, NN);

    // ---- tables ----
    f2bf_kernel<<<(NN * 16 + 255) / 256, 256, 0, stream>>>(x, xb, NN * 16);
    wprep_kernel<<<(3 * 64 * 128 + 255) / 256, 256, 0, stream>>>(Wl0, Wr0, Wl1, Wr1, Wl2, Wr2, wcat);

    const int aggGrid = (NN * 8 + 255) / 256;   // 8 lanes per node
    const int linGrid = (NN + 63) / 64;

    // layer 0
    aggregate_bf16<<<aggGrid, 256, 0, stream>>>(xb, rowptr, esrc, meanb, NN);
    sage_linear_mfma<<<linGrid, 256, 0, stream>>>(meanb, xb, wcat, bl0, nullptr, hbA, NN, 1);

    // layer 1
    aggregate_bf16<<<aggGrid, 256, 0, stream>>>(hbA, rowptr, esrc, meanb, NN);
    sage_linear_mfma<<<linGrid, 256, 0, stream>>>(meanb, hbA, wcat + 8192, bl1, nullptr, hbB, NN, 1);

    // layer 2
    aggregate_bf16<<<aggGrid, 256, 0, stream>>>(hbB, rowptr, esrc, meanb, NN);
    sage_linear_mfma<<<linGrid, 256, 0, stream>>>(meanb, hbB, wcat + 16384, bl2, out, nullptr, NN, 0);
}

// Round 9
// 207.731 us; speedup vs baseline: 21.6828x; 1.1090x over previous
//
#include <hip/hip_runtime.h>

#define NN 100000
#define NE 1600000
#define D 64

#define NBUCK ((NN + 255) / 256)              // 391 buckets of 256 nodes
#define EPB 4096                               // edges per partition block
#define P1_BLOCKS ((NE + EPB - 1) / EPB)       // 391
#define BCAP 6144                              // max edges per bucket

#define F2BF_BLOCKS (NN * 16 / 256)            // 6250 (NN*16 float4 elems)
#define WPREP_BLOCKS (3 * 64 * 128 / 256)      // 96
#define ZERO_BLOCKS ((NBUCK + 255) / 256)      // 2

typedef __attribute__((ext_vector_type(8))) short bfrag;   // 8 bf16 = 4 VGPR
typedef __attribute__((ext_vector_type(4))) float f4acc;   // 4 fp32 acc

__device__ __forceinline__ unsigned short f2bf(float f) {
    unsigned u = __float_as_uint(f);
    u = (u + 0x7FFFu + ((u >> 16) & 1u)) >> 16;  // RNE
    return (unsigned short)u;
}

// ---------------- prep: f2bf(x) + weight concat + zero bucket_cnt, one launch ----
__global__ __launch_bounds__(256) void prep_kernel(
    const float* __restrict__ x, unsigned short* __restrict__ xb,
    const float* __restrict__ Wl0, const float* __restrict__ Wr0,
    const float* __restrict__ Wl1, const float* __restrict__ Wr1,
    const float* __restrict__ Wl2, const float* __restrict__ Wr2,
    unsigned short* __restrict__ wcat, int* __restrict__ bucket_cnt) {
    int b = blockIdx.x;
    int t = threadIdx.x;
    if (b < F2BF_BLOCKS) {
        int i = b * 256 + t;  // < NN*16
        float4 v = ((const float4*)x)[i];
        ushort4 o;
        o.x = f2bf(v.x); o.y = f2bf(v.y); o.z = f2bf(v.z); o.w = f2bf(v.w);
        ((ushort4*)xb)[i] = o;
    } else if (b < F2BF_BLOCKS + WPREP_BLOCKS) {
        int i = (b - F2BF_BLOCKS) * 256 + t;  // < 3*64*128
        int layer = i >> 13;
        int rem = i & 8191;
        int n = rem >> 7;
        int k = rem & 127;
        const float* W;
        if (layer == 0) W = (k < 64) ? Wl0 : Wr0;
        else if (layer == 1) W = (k < 64) ? Wl1 : Wr1;
        else W = (k < 64) ? Wl2 : Wr2;
        wcat[i] = f2bf(W[n * 64 + (k & 63)]);
    } else {
        int i = (b - F2BF_BLOCKS - WPREP_BLOCKS) * 256 + t;
        if (i < NBUCK) bucket_cnt[i] = 0;
    }
}

// ---------------- CSR build: bucketed counting sort ----------------
__global__ __launch_bounds__(256) void p0_bucket_hist(const int* __restrict__ dst,
                                                      int* __restrict__ bucket_cnt, int nE) {
    __shared__ int h[NBUCK];
    int t = threadIdx.x;
    for (int i = t; i < NBUCK; i += 256) h[i] = 0;
    __syncthreads();
    int base = blockIdx.x * EPB;
    for (int i = t; i < EPB; i += 256) {
        int e = base + i;
        if (e < nE) atomicAdd(&h[dst[e] >> 8], 1);
    }
    __syncthreads();
    for (int i = t; i < NBUCK; i += 256)
        if (h[i]) atomicAdd(&bucket_cnt[i], h[i]);
}

__global__ __launch_bounds__(512) void bucket_scan(const int* __restrict__ bucket_cnt,
                                                   int* __restrict__ bucket_off,
                                                   int* __restrict__ bucket_cur,
                                                   int* __restrict__ rowptr) {
    __shared__ int s[512];
    int t = threadIdx.x;
    int v = (t < NBUCK) ? bucket_cnt[t] : 0;
    s[t] = v;
    __syncthreads();
    for (int off = 1; off < 512; off <<= 1) {
        int u = (t >= off) ? s[t - off] : 0;
        __syncthreads();
        s[t] += u;
        __syncthreads();
    }
    if (t < NBUCK) { bucket_off[t] = s[t] - v; bucket_cur[t] = s[t] - v; }
    if (t == NBUCK - 1) { bucket_off[NBUCK] = s[t]; rowptr[NN] = s[t]; }
}

__global__ __launch_bounds__(256) void p1_partition(const int* __restrict__ src,
                                                    const int* __restrict__ dst,
                                                    int* __restrict__ bucket_cur,
                                                    unsigned* __restrict__ packed, int nE) {
    __shared__ int h[NBUCK];
    int t = threadIdx.x;
    for (int i = t; i < NBUCK; i += 256) h[i] = 0;
    __syncthreads();
    int base = blockIdx.x * EPB;
    for (int i = t; i < EPB; i += 256) {
        int e = base + i;
        if (e < nE) atomicAdd(&h[dst[e] >> 8], 1);
    }
    __syncthreads();
    for (int i = t; i < NBUCK; i += 256) {
        int c = h[i];
        h[i] = c ? atomicAdd(&bucket_cur[i], c) : 0;
    }
    __syncthreads();
    for (int i = t; i < EPB; i += 256) {
        int e = base + i;
        if (e < nE) {
            int d = dst[e];
            int pos = atomicAdd(&h[d >> 8], 1);
            packed[pos] = ((unsigned)(d & 255) << 24) | (unsigned)src[e];
        }
    }
}

// p2b: per-bucket histogram + local scan -> rowptr write; in-LDS counting sort -> esrc
__global__ __launch_bounds__(256) void p2b_place(const unsigned* __restrict__ packed,
                                                 const int* __restrict__ bucket_off,
                                                 int* __restrict__ rowptr,
                                                 int* __restrict__ esrc, int nNodes) {
    __shared__ int h[256];
    __shared__ int cur[256];
    __shared__ int sl[BCAP];
    int b = blockIdx.x, t = threadIdx.x;
    h[t] = 0;
    __syncthreads();
    int lo = bucket_off[b], hi = bucket_off[b + 1];
    int cnt = hi - lo;
    for (int i = lo + t; i < hi; i += 256) atomicAdd(&h[packed[i] >> 24], 1);
    __syncthreads();
    int v = h[t];
    for (int off = 1; off < 256; off <<= 1) {
        int u = (t >= off) ? h[t - off] : 0;
        __syncthreads();
        h[t] += u;
        __syncthreads();
    }
    int excl = h[t] - v;
    cur[t] = excl;
    int node = b * 256 + t;
    if (node < nNodes) rowptr[node] = lo + excl;
    __syncthreads();
    for (int i = lo + t; i < hi; i += 256) {
        unsigned p = packed[i];
        int pos = atomicAdd(&cur[p >> 24], 1);
        if (pos < BCAP) sl[pos] = (int)(p & 0xFFFFFFu);
    }
    __syncthreads();
    for (int i = t; i < cnt; i += 256) esrc[lo + i] = sl[i];
}

// ---------------- fused layer: gather-mean (LDS) + MFMA dual-linear ----------------
// 512 threads = 64 nodes. Phase 1: 8 lanes/node gather bf16 rows, fp32 accum,
// write bf16 mean into XOR-swizzled LDS tile. Phase 2: 8 waves x (2 row-tiles,
// 16 cols each) MFMA over K=128 concat [mean | root].
__global__ __launch_bounds__(512) void sage_layer(
    const unsigned short* __restrict__ xb,   // gather table == root features
    const int* __restrict__ rowptr, const int* __restrict__ esrc,
    const unsigned short* __restrict__ wcat,  // [64][128] bf16, this layer
    const float* __restrict__ bl,
    float* __restrict__ outF,                 // may be null
    unsigned short* __restrict__ outB,        // may be null
    int nNodes, int doRelu) {
    __shared__ unsigned short smean[64 * 64];  // bf16 [row][col], col ^= (row&7)<<3

    int t = threadIdx.x;
    // ---- phase 1: gather + mean ----
    {
        int nl = t >> 3;            // node local 0..63
        int q = t & 7;              // channel octet
        int lane = t & 63;
        int gbase = lane & 56;
        int node = blockIdx.x * 64 + nl;
        uint4 o = make_uint4(0, 0, 0, 0);
        if (node < nNodes) {
            int rs = rowptr[node];
            int re = rowptr[node + 1];
            float a0 = 0, a1 = 0, a2 = 0, a3 = 0, a4 = 0, a5 = 0, a6 = 0, a7 = 0;
            for (int i = rs; i < re; i += 8) {
                int ei = i + q;
                int mySrc = (ei < re) ? esrc[ei] : -1;
#pragma unroll
                for (int j = 0; j < 8; ++j) {
                    int s = __shfl(mySrc, gbase + j, 64);
                    if (s < 0) break;  // uniform within the 8-lane group
                    uint4 w = ((const uint4*)xb)[s * 8 + q];
                    a0 += __uint_as_float(w.x << 16);
                    a1 += __uint_as_float(w.x & 0xFFFF0000u);
                    a2 += __uint_as_float(w.y << 16);
                    a3 += __uint_as_float(w.y & 0xFFFF0000u);
                    a4 += __uint_as_float(w.z << 16);
                    a5 += __uint_as_float(w.z & 0xFFFF0000u);
                    a6 += __uint_as_float(w.w << 16);
                    a7 += __uint_as_float(w.w & 0xFFFF0000u);
                }
            }
            float inv = 1.0f / fmaxf((float)(re - rs), 1.0f);
            o.x = (unsigned)f2bf(a0 * inv) | ((unsigned)f2bf(a1 * inv) << 16);
            o.y = (unsigned)f2bf(a2 * inv) | ((unsigned)f2bf(a3 * inv) << 16);
            o.z = (unsigned)f2bf(a4 * inv) | ((unsigned)f2bf(a5 * inv) << 16);
            o.w = (unsigned)f2bf(a6 * inv) | ((unsigned)f2bf(a7 * inv) << 16);
        }
        int idx = nl * 64 + ((q * 8) ^ ((nl & 7) << 3));  // swizzled, 16B aligned
        *(uint4*)&smean[idx] = o;
    }
    __syncthreads();

    // ---- phase 2: MFMA ----
    int w = t >> 6;
    int l = t & 63;
    int lr = l & 15;   // A row-in-tile / B col / C col
    int lk = l >> 4;   // k-group
    int cg = w & 3;    // col group

    const bfrag* wB = (const bfrag*)wcat;  // 16 frags per 128-k row
    int n = cg * 16 + lr;                  // output channel
    bfrag b0 = wB[n * 16 + lk];
    bfrag b1 = wB[n * 16 + 4 + lk];
    bfrag b2 = wB[n * 16 + 8 + lk];
    bfrag b3 = wB[n * 16 + 12 + lk];
    float bias = bl[n];

    int base = blockIdx.x * 64;
#pragma unroll
    for (int rr = 0; rr < 2; ++rr) {
        int rt = (w >> 2) + rr * 2;  // row tile 0..3 (2 per wave)
        int row0 = base + rt * 16;
        int lrow = rt * 16 + lr;
        int sw = (lrow & 7) << 3;
        bfrag a0 = *(const bfrag*)&smean[lrow * 64 + ((lk * 8) ^ sw)];
        bfrag a1 = *(const bfrag*)&smean[lrow * 64 + ((32 + lk * 8) ^ sw)];
        int grow = row0 + lr;
        if (grow >= nNodes) grow = nNodes - 1;  // clamp (stores guarded below)
        const bfrag* xr = (const bfrag*)(xb + (size_t)grow * D);
        bfrag a2 = xr[lk];
        bfrag a3 = xr[4 + lk];
        f4acc acc = {0.f, 0.f, 0.f, 0.f};
        acc = __builtin_amdgcn_mfma_f32_16x16x32_bf16(a0, b0, acc, 0, 0, 0);
        acc = __builtin_amdgcn_mfma_f32_16x16x32_bf16(a1, b1, acc, 0, 0, 0);
        acc = __builtin_amdgcn_mfma_f32_16x16x32_bf16(a2, b2, acc, 0, 0, 0);
        acc = __builtin_amdgcn_mfma_f32_16x16x32_bf16(a3, b3, acc, 0, 0, 0);
#pragma unroll
        for (int r = 0; r < 4; ++r) {
            int row = row0 + lk * 4 + r;
            if (row >= nNodes) continue;
            float v = acc[r] + bias;
            if (doRelu) v = fmaxf(v, 0.f);
            if (outF) outF[(size_t)row * D + n] = v;
            if (outB) outB[(size_t)row * D + n] = f2bf(v);
        }
    }
}

extern "C" void kernel_launch(void* const* d_in, const int* in_sizes, int n_in,
                              void* d_out, int out_size, void* d_ws, size_t ws_size,
                              hipStream_t stream) {
    const float* x   = (const float*)d_in[0];
    const int*   src = (const int*)d_in[1];
    const int*   dst = (const int*)d_in[2];
    const float* Wl0 = (const float*)d_in[3];
    const float* bl0 = (const float*)d_in[4];
    const float* Wr0 = (const float*)d_in[5];
    const float* Wl1 = (const float*)d_in[6];
    const float* bl1 = (const float*)d_in[7];
    const float* Wr1 = (const float*)d_in[8];
    const float* Wl2 = (const float*)d_in[9];
    const float* bl2 = (const float*)d_in[10];
    const float* Wr2 = (const float*)d_in[11];
    float* out = (float*)d_out;

    const size_t bfeatBytes = (size_t)NN * D * 2;  // 12.8 MB (bf16 table)
    char* ws = (char*)d_ws;
    int* bucket_cnt = (int*)(ws);
    int* bucket_off = (int*)(ws + (16 << 10));
    int* bucket_cur = (int*)(ws + (32 << 10));
    unsigned short* wcat = (unsigned short*)(ws + (128 << 10));  // 48 KB
    int* rowptr     = (int*)(ws + (1 << 20));        // NN+1
    int* esrc       = (int*)(ws + (2 << 20));        // NE (6.4 MB)
    char* big = ws + (9 << 20);
    unsigned* packed = (unsigned*)big;                                  // 6.4 MB (CSR build only)
    unsigned short* xb  = (unsigned short*)(big + bfeatBytes);          // 12.8 MB
    unsigned short* hbA = (unsigned short*)(big + 2 * bfeatBytes);      // 12.8 MB
    unsigned short* hbB = (unsigned short*)(big + 3 * bfeatBytes);      // 12.8 MB

    // ---- prep (f2bf + wprep + zero) ----
    prep_kernel<<<F2BF_BLOCKS + WPREP_BLOCKS + ZERO_BLOCKS, 256, 0, stream>>>(
        x, xb, Wl0, Wr0, Wl1, Wr1, Wl2, Wr2, wcat, bucket_cnt);

    // ---- CSR build ----
    p0_bucket_hist<<<P1_BLOCKS, 256, 0, stream>>>(dst, bucket_cnt, NE);
    bucket_scan<<<1, 512, 0, stream>>>(bucket_cnt, bucket_off, bucket_cur, rowptr);
    p1_partition<<<P1_BLOCKS, 256, 0, stream>>>(src, dst, bucket_cur, packed, NE);
    p2b_place<<<NBUCK, 256, 0, stream>>>(packed, bucket_off, rowptr, esrc, NN);

    // ---- fused layers ----
    const int layerGrid = (NN + 63) / 64;
    sage_layer<<<layerGrid, 512, 0, stream>>>(xb,  rowptr, esrc, wcat,         bl0, nullptr, hbA, NN, 1);
    sage_layer<<<layerGrid, 512, 0, stream>>>(hbA, rowptr, esrc, wcat + 8192,  bl1, nullptr, hbB, NN, 1);
    sage_layer<<<layerGrid, 512, 0, stream>>>(hbB, rowptr, esrc, wcat + 16384, bl2, out, nullptr, NN, 0);
}

// Round 10
// 200.688 us; speedup vs baseline: 22.4438x; 1.0351x over previous
//
#include <hip/hip_runtime.h>

#define NN 100000
#define NE 1600000
#define D 64

#define NBUCK ((NN + 255) / 256)              // 391 buckets of 256 nodes
#define EPB 4096                               // edges per partition block
#define P1_BLOCKS ((NE + EPB - 1) / EPB)       // 391
#define BCAP 6144                              // max edges per bucket

#define F2BF_BLOCKS (NN * 16 / 256)            // 6250 (NN*16 float4 elems)
#define WPREP_BLOCKS (3 * 64 * 128 / 256)      // 96
#define ZERO_BLOCKS ((NBUCK + 255) / 256)      // 2

typedef __attribute__((ext_vector_type(8))) short bfrag;   // 8 bf16 = 4 VGPR
typedef __attribute__((ext_vector_type(4))) float f4acc;   // 4 fp32 acc

__device__ __forceinline__ unsigned short f2bf(float f) {
    unsigned u = __float_as_uint(f);
    u = (u + 0x7FFFu + ((u >> 16) & 1u)) >> 16;  // RNE
    return (unsigned short)u;
}

// ---------------- prep: f2bf(x) + weight concat + zero bucket_cnt, one launch ----
__global__ __launch_bounds__(256) void prep_kernel(
    const float* __restrict__ x, unsigned short* __restrict__ xb,
    const float* __restrict__ Wl0, const float* __restrict__ Wr0,
    const float* __restrict__ Wl1, const float* __restrict__ Wr1,
    const float* __restrict__ Wl2, const float* __restrict__ Wr2,
    unsigned short* __restrict__ wcat, int* __restrict__ bucket_cnt) {
    int b = blockIdx.x;
    int t = threadIdx.x;
    if (b < F2BF_BLOCKS) {
        int i = b * 256 + t;  // < NN*16
        float4 v = ((const float4*)x)[i];
        ushort4 o;
        o.x = f2bf(v.x); o.y = f2bf(v.y); o.z = f2bf(v.z); o.w = f2bf(v.w);
        ((ushort4*)xb)[i] = o;
    } else if (b < F2BF_BLOCKS + WPREP_BLOCKS) {
        int i = (b - F2BF_BLOCKS) * 256 + t;  // < 3*64*128
        int layer = i >> 13;
        int rem = i & 8191;
        int n = rem >> 7;
        int k = rem & 127;
        const float* W;
        if (layer == 0) W = (k < 64) ? Wl0 : Wr0;
        else if (layer == 1) W = (k < 64) ? Wl1 : Wr1;
        else W = (k < 64) ? Wl2 : Wr2;
        wcat[i] = f2bf(W[n * 64 + (k & 63)]);
    } else {
        int i = (b - F2BF_BLOCKS - WPREP_BLOCKS) * 256 + t;
        if (i < NBUCK) bucket_cnt[i] = 0;
    }
}

// ---------------- CSR build: bucketed counting sort ----------------
__global__ __launch_bounds__(256) void p0_bucket_hist(const int* __restrict__ dst,
                                                      int* __restrict__ bucket_cnt, int nE) {
    __shared__ int h[NBUCK];
    int t = threadIdx.x;
    for (int i = t; i < NBUCK; i += 256) h[i] = 0;
    __syncthreads();
    int base = blockIdx.x * EPB;
    for (int i = t; i < EPB; i += 256) {
        int e = base + i;
        if (e < nE) atomicAdd(&h[dst[e] >> 8], 1);
    }
    __syncthreads();
    for (int i = t; i < NBUCK; i += 256)
        if (h[i]) atomicAdd(&bucket_cnt[i], h[i]);
}

__global__ __launch_bounds__(512) void bucket_scan(const int* __restrict__ bucket_cnt,
                                                   int* __restrict__ bucket_off,
                                                   int* __restrict__ bucket_cur,
                                                   int* __restrict__ rowptr) {
    __shared__ int s[512];
    int t = threadIdx.x;
    int v = (t < NBUCK) ? bucket_cnt[t] : 0;
    s[t] = v;
    __syncthreads();
    for (int off = 1; off < 512; off <<= 1) {
        int u = (t >= off) ? s[t - off] : 0;
        __syncthreads();
        s[t] += u;
        __syncthreads();
    }
    if (t < NBUCK) { bucket_off[t] = s[t] - v; bucket_cur[t] = s[t] - v; }
    if (t == NBUCK - 1) { bucket_off[NBUCK] = s[t]; rowptr[NN] = s[t]; }
}

__global__ __launch_bounds__(256) void p1_partition(const int* __restrict__ src,
                                                    const int* __restrict__ dst,
                                                    int* __restrict__ bucket_cur,
                                                    unsigned* __restrict__ packed, int nE) {
    __shared__ int h[NBUCK];
    int t = threadIdx.x;
    for (int i = t; i < NBUCK; i += 256) h[i] = 0;
    __syncthreads();
    int base = blockIdx.x * EPB;
    for (int i = t; i < EPB; i += 256) {
        int e = base + i;
        if (e < nE) atomicAdd(&h[dst[e] >> 8], 1);
    }
    __syncthreads();
    for (int i = t; i < NBUCK; i += 256) {
        int c = h[i];
        h[i] = c ? atomicAdd(&bucket_cur[i], c) : 0;
    }
    __syncthreads();
    for (int i = t; i < EPB; i += 256) {
        int e = base + i;
        if (e < nE) {
            int d = dst[e];
            int pos = atomicAdd(&h[d >> 8], 1);
            packed[pos] = ((unsigned)(d & 255) << 24) | (unsigned)src[e];
        }
    }
}

// p2b: per-bucket histogram + local scan -> rowptr write; in-LDS counting sort -> esrc
__global__ __launch_bounds__(256) void p2b_place(const unsigned* __restrict__ packed,
                                                 const int* __restrict__ bucket_off,
                                                 int* __restrict__ rowptr,
                                                 int* __restrict__ esrc, int nNodes) {
    __shared__ int h[256];
    __shared__ int cur[256];
    __shared__ int sl[BCAP];
    int b = blockIdx.x, t = threadIdx.x;
    h[t] = 0;
    __syncthreads();
    int lo = bucket_off[b], hi = bucket_off[b + 1];
    int cnt = hi - lo;
    for (int i = lo + t; i < hi; i += 256) atomicAdd(&h[packed[i] >> 24], 1);
    __syncthreads();
    int v = h[t];
    for (int off = 1; off < 256; off <<= 1) {
        int u = (t >= off) ? h[t - off] : 0;
        __syncthreads();
        h[t] += u;
        __syncthreads();
    }
    int excl = h[t] - v;
    cur[t] = excl;
    int node = b * 256 + t;
    if (node < nNodes) rowptr[node] = lo + excl;
    __syncthreads();
    for (int i = lo + t; i < hi; i += 256) {
        unsigned p = packed[i];
        int pos = atomicAdd(&cur[p >> 24], 1);
        if (pos < BCAP) sl[pos] = (int)(p & 0xFFFFFFu);
    }
    __syncthreads();
    for (int i = t; i < cnt; i += 256) esrc[lo + i] = sl[i];
}

// ---------------- fused layer: gather-mean (LDS) + MFMA dual-linear ----------------
// 256 threads = 32 nodes. Phase 1: 8 lanes/node; branch-free batches of 8 edges:
// coalesced esrc load -> 8 batched shfl broadcasts -> 8 unconditional 16B gathers
// in flight, predicated accumulate. Phase 2: 4 waves x (2 row-tiles, 16 cols) MFMA.
__global__ __launch_bounds__(256) void sage_layer(
    const unsigned short* __restrict__ xb,   // gather table == root features
    const int* __restrict__ rowptr, const int* __restrict__ esrc,
    const unsigned short* __restrict__ wcat,  // [64][128] bf16, this layer
    const float* __restrict__ bl,
    float* __restrict__ outF,                 // may be null
    unsigned short* __restrict__ outB,        // may be null
    int nNodes, int doRelu) {
    __shared__ unsigned short smean[32 * 64];  // bf16 [row][col], col ^= (row&7)<<3

    int t = threadIdx.x;
    // ---- phase 1: gather + mean ----
    {
        int nl = t >> 3;            // node local 0..31
        int q = t & 7;              // channel octet
        int lane = t & 63;
        int gbase = lane & 56;
        int node = blockIdx.x * 32 + nl;
        uint4 o = make_uint4(0, 0, 0, 0);
        if (node < nNodes) {
            int rs = rowptr[node];
            int re = rowptr[node + 1];
            float a0 = 0, a1 = 0, a2 = 0, a3 = 0, a4 = 0, a5 = 0, a6 = 0, a7 = 0;
            for (int i = rs; i < re; i += 8) {
                int ei = i + q;
                int mySrc = esrc[ei < NE ? ei : (NE - 1)];  // coalesced; clamped tail
                int s[8];
#pragma unroll
                for (int j = 0; j < 8; ++j) s[j] = __shfl(mySrc, gbase + j, 64);
#pragma unroll
                for (int j = 0; j < 8; ++j) {
                    uint4 w = ((const uint4*)xb)[s[j] * 8 + q];  // unconditional issue
                    if (i + j < re) {
                        a0 += __uint_as_float(w.x << 16);
                        a1 += __uint_as_float(w.x & 0xFFFF0000u);
                        a2 += __uint_as_float(w.y << 16);
                        a3 += __uint_as_float(w.y & 0xFFFF0000u);
                        a4 += __uint_as_float(w.z << 16);
                        a5 += __uint_as_float(w.z & 0xFFFF0000u);
                        a6 += __uint_as_float(w.w << 16);
                        a7 += __uint_as_float(w.w & 0xFFFF0000u);
                    }
                }
            }
            float inv = 1.0f / fmaxf((float)(re - rs), 1.0f);
            o.x = (unsigned)f2bf(a0 * inv) | ((unsigned)f2bf(a1 * inv) << 16);
            o.y = (unsigned)f2bf(a2 * inv) | ((unsigned)f2bf(a3 * inv) << 16);
            o.z = (unsigned)f2bf(a4 * inv) | ((unsigned)f2bf(a5 * inv) << 16);
            o.w = (unsigned)f2bf(a6 * inv) | ((unsigned)f2bf(a7 * inv) << 16);
        }
        int idx = nl * 64 + ((q * 8) ^ ((nl & 7) << 3));  // swizzled, 16B aligned
        *(uint4*)&smean[idx] = o;
    }
    __syncthreads();

    // ---- phase 2: MFMA ----
    int w = t >> 6;    // wave 0..3 = col group
    int l = t & 63;
    int lr = l & 15;   // A row-in-tile / B col / C col
    int lk = l >> 4;   // k-group

    const bfrag* wB = (const bfrag*)wcat;  // 16 frags per 128-k row
    int n = w * 16 + lr;                   // output channel
    bfrag b0 = wB[n * 16 + lk];
    bfrag b1 = wB[n * 16 + 4 + lk];
    bfrag b2 = wB[n * 16 + 8 + lk];
    bfrag b3 = wB[n * 16 + 12 + lk];
    float bias = bl[n];

    int base = blockIdx.x * 32;
#pragma unroll
    for (int rt = 0; rt < 2; ++rt) {
        int row0 = base + rt * 16;
        int lrow = rt * 16 + lr;
        int sw = (lrow & 7) << 3;
        bfrag a0 = *(const bfrag*)&smean[lrow * 64 + ((lk * 8) ^ sw)];
        bfrag a1 = *(const bfrag*)&smean[lrow * 64 + ((32 + lk * 8) ^ sw)];
        int grow = row0 + lr;
        if (grow >= nNodes) grow = nNodes - 1;  // clamp (stores guarded below)
        const bfrag* xr = (const bfrag*)(xb + (size_t)grow * D);
        bfrag a2 = xr[lk];
        bfrag a3 = xr[4 + lk];
        f4acc acc = {0.f, 0.f, 0.f, 0.f};
        acc = __builtin_amdgcn_mfma_f32_16x16x32_bf16(a0, b0, acc, 0, 0, 0);
        acc = __builtin_amdgcn_mfma_f32_16x16x32_bf16(a1, b1, acc, 0, 0, 0);
        acc = __builtin_amdgcn_mfma_f32_16x16x32_bf16(a2, b2, acc, 0, 0, 0);
        acc = __builtin_amdgcn_mfma_f32_16x16x32_bf16(a3, b3, acc, 0, 0, 0);
#pragma unroll
        for (int r = 0; r < 4; ++r) {
            int row = row0 + lk * 4 + r;
            if (row >= nNodes) continue;
            float v = acc[r] + bias;
            if (doRelu) v = fmaxf(v, 0.f);
            if (outF) outF[(size_t)row * D + n] = v;
            if (outB) outB[(size_t)row * D + n] = f2bf(v);
        }
    }
}

extern "C" void kernel_launch(void* const* d_in, const int* in_sizes, int n_in,
                              void* d_out, int out_size, void* d_ws, size_t ws_size,
                              hipStream_t stream) {
    const float* x   = (const float*)d_in[0];
    const int*   src = (const int*)d_in[1];
    const int*   dst = (const int*)d_in[2];
    const float* Wl0 = (const float*)d_in[3];
    const float* bl0 = (const float*)d_in[4];
    const float* Wr0 = (const float*)d_in[5];
    const float* Wl1 = (const float*)d_in[6];
    const float* bl1 = (const float*)d_in[7];
    const float* Wr1 = (const float*)d_in[8];
    const float* Wl2 = (const float*)d_in[9];
    const float* bl2 = (const float*)d_in[10];
    const float* Wr2 = (const float*)d_in[11];
    float* out = (float*)d_out;

    const size_t bfeatBytes = (size_t)NN * D * 2;  // 12.8 MB (bf16 table)
    char* ws = (char*)d_ws;
    int* bucket_cnt = (int*)(ws);
    int* bucket_off = (int*)(ws + (16 << 10));
    int* bucket_cur = (int*)(ws + (32 << 10));
    unsigned short* wcat = (unsigned short*)(ws + (128 << 10));  // 48 KB
    int* rowptr     = (int*)(ws + (1 << 20));        // NN+1
    int* esrc       = (int*)(ws + (2 << 20));        // NE (6.4 MB)
    char* big = ws + (9 << 20);
    unsigned* packed = (unsigned*)big;                                  // 6.4 MB (CSR build only)
    unsigned short* xb  = (unsigned short*)(big + bfeatBytes);          // 12.8 MB
    unsigned short* hbA = (unsigned short*)(big + 2 * bfeatBytes);      // 12.8 MB
    unsigned short* hbB = (unsigned short*)(big + 3 * bfeatBytes);      // 12.8 MB

    // ---- prep (f2bf + wprep + zero) ----
    prep_kernel<<<F2BF_BLOCKS + WPREP_BLOCKS + ZERO_BLOCKS, 256, 0, stream>>>(
        x, xb, Wl0, Wr0, Wl1, Wr1, Wl2, Wr2, wcat, bucket_cnt);

    // ---- CSR build ----
    p0_bucket_hist<<<P1_BLOCKS, 256, 0, stream>>>(dst, bucket_cnt, NE);
    bucket_scan<<<1, 512, 0, stream>>>(bucket_cnt, bucket_off, bucket_cur, rowptr);
    p1_partition<<<P1_BLOCKS, 256, 0, stream>>>(src, dst, bucket_cur, packed, NE);
    p2b_place<<<NBUCK, 256, 0, stream>>>(packed, bucket_off, rowptr, esrc, NN);

    // ---- fused layers ----
    const int layerGrid = (NN + 31) / 32;
    sage_layer<<<layerGrid, 256, 0, stream>>>(xb,  rowptr, esrc, wcat,         bl0, nullptr, hbA, NN, 1);
    sage_layer<<<layerGrid, 256, 0, stream>>>(hbA, rowptr, esrc, wcat + 8192,  bl1, nullptr, hbB, NN, 1);
    sage_layer<<<layerGrid, 256, 0, stream>>>(hbB, rowptr, esrc, wcat + 16384, bl2, out, nullptr, NN, 0);
}

// Round 12
// 193.833 us; speedup vs baseline: 23.2374x; 1.0354x over previous
//
#include <hip/hip_runtime.h>

#define NN 100000
#define NE 1600000
#define D 64

#define NBUCK ((NN + 255) / 256)              // 391 buckets of 256 nodes
#define EPB 4096                               // edges per partition block
#define P1_BLOCKS ((NE + EPB - 1) / EPB)       // 391
#define BCAP 6144                              // fixed bucket capacity (avg 4096, sigma 64)

#define F2BF_BLOCKS (NN * 16 / 256)            // 6250 (NN*16 float4 elems)
#define WPREP_BLOCKS (3 * 64 * 128 / 256)      // 96
#define ZERO_BLOCKS ((NBUCK + 255) / 256)      // 2

typedef __attribute__((ext_vector_type(8))) short bfrag;   // 8 bf16 = 4 VGPR
typedef __attribute__((ext_vector_type(4))) float f4acc;   // 4 fp32 acc

__device__ __forceinline__ unsigned short f2bf(float f) {
    unsigned u = __float_as_uint(f);
    u = (u + 0x7FFFu + ((u >> 16) & 1u)) >> 16;  // RNE
    return (unsigned short)u;
}

// ---------------- prep: f2bf(x) + weight concat + zero bucket_cur, one launch ----
__global__ __launch_bounds__(256) void prep_kernel(
    const float* __restrict__ x, unsigned short* __restrict__ xb,
    const float* __restrict__ Wl0, const float* __restrict__ Wr0,
    const float* __restrict__ Wl1, const float* __restrict__ Wr1,
    const float* __restrict__ Wl2, const float* __restrict__ Wr2,
    unsigned short* __restrict__ wcat, int* __restrict__ bucket_cur) {
    int b = blockIdx.x;
    int t = threadIdx.x;
    if (b < F2BF_BLOCKS) {
        int i = b * 256 + t;  // < NN*16
        float4 v = ((const float4*)x)[i];
        ushort4 o;
        o.x = f2bf(v.x); o.y = f2bf(v.y); o.z = f2bf(v.z); o.w = f2bf(v.w);
        ((ushort4*)xb)[i] = o;
    } else if (b < F2BF_BLOCKS + WPREP_BLOCKS) {
        int i = (b - F2BF_BLOCKS) * 256 + t;  // < 3*64*128
        int layer = i >> 13;
        int rem = i & 8191;
        int n = rem >> 7;
        int k = rem & 127;
        const float* W;
        if (layer == 0) W = (k < 64) ? Wl0 : Wr0;
        else if (layer == 1) W = (k < 64) ? Wl1 : Wr1;
        else W = (k < 64) ? Wl2 : Wr2;
        wcat[i] = f2bf(W[n * 64 + (k & 63)]);
    } else {
        int i = (b - F2BF_BLOCKS - WPREP_BLOCKS) * 256 + t;
        if (i < NBUCK) bucket_cur[i] = 0;
    }
}

// ---------------- p1: partition edges into fixed-capacity bucket regions ----------
// Block-local counting sort in LDS, then coalesced run flush (no random 4B scatter).
__global__ __launch_bounds__(256) void p1_partition(const int* __restrict__ src,
                                                    const int* __restrict__ dst,
                                                    int* __restrict__ bucket_cur,
                                                    unsigned* __restrict__ packed, int nE) {
    __shared__ int h[NBUCK];        // hist, then per-bucket reserved global offset
    __shared__ int ls[512];         // padded inclusive scan
    __shared__ int lstart[NBUCK];   // local exclusive starts
    __shared__ int lcur[NBUCK];     // local cursors
    __shared__ unsigned sl[EPB];    // staged packed words (16 KB)
    int t = threadIdx.x;
    for (int i = t; i < NBUCK; i += 256) h[i] = 0;
    __syncthreads();
    int base = blockIdx.x * EPB;
    int cnt = min(EPB, nE - base);
    for (int i = t; i < cnt; i += 256) atomicAdd(&h[dst[base + i] >> 8], 1);
    __syncthreads();
    // block-local inclusive scan over padded 512 (256 threads, 2 slots each)
    ls[t] = h[t];
    ls[t + 256] = (t + 256 < NBUCK) ? h[t + 256] : 0;
    __syncthreads();
    for (int off = 1; off < 512; off <<= 1) {
        int a = (t >= off) ? ls[t - off] : 0;
        int b2 = (t + 256 >= off) ? ls[t + 256 - off] : 0;
        __syncthreads();
        ls[t] += a;
        ls[t + 256] += b2;
        __syncthreads();
    }
    // exclusive starts, local cursors, global range reservation
    for (int i = t; i < NBUCK; i += 256) {
        int c = h[i];
        int excl = ls[i] - c;
        lstart[i] = excl;
        lcur[i] = excl;
        h[i] = c ? atomicAdd(&bucket_cur[i], c) : 0;  // offset within bucket region
    }
    __syncthreads();
    // place into staging (bucket-sorted within block)
    for (int i = t; i < cnt; i += 256) {
        int d = dst[base + i];
        int pos = atomicAdd(&lcur[d >> 8], 1);
        sl[pos] = ((unsigned)(d & 255) << 24) | (unsigned)src[base + i];
    }
    __syncthreads();
    // flush: contiguous per-bucket runs -> packed[b*BCAP + reserved + run-offset]
    for (int j = t; j < cnt; j += 256) {
        int lo2 = 0, hi2 = NBUCK;  // largest b with lstart[b] <= j
        while (hi2 - lo2 > 1) {
            int mid = (lo2 + hi2) >> 1;
            if (lstart[mid] <= j) lo2 = mid; else hi2 = mid;
        }
        packed[lo2 * BCAP + h[lo2] + (j - lstart[lo2])] = sl[j];
    }
}

// p2b: per-bucket hist + local scan -> rowpair(start,end); in-LDS sort -> esrc (+pad)
__global__ __launch_bounds__(256) void p2b_place(const unsigned* __restrict__ packed,
                                                 const int* __restrict__ bucket_cur,
                                                 int2* __restrict__ rowpair,
                                                 int* __restrict__ esrc, int nNodes) {
    __shared__ int h[256];
    __shared__ int cur[256];
    __shared__ int sl[BCAP];
    int b = blockIdx.x, t = threadIdx.x;
    h[t] = 0;
    __syncthreads();
    int lo = b * BCAP;
    int cnt = bucket_cur[b];
    for (int i = t; i < cnt; i += 256) atomicAdd(&h[packed[lo + i] >> 24], 1);
    __syncthreads();
    int v = h[t];
    for (int off = 1; off < 256; off <<= 1) {
        int u = (t >= off) ? h[t - off] : 0;
        __syncthreads();
        h[t] += u;
        __syncthreads();
    }
    int incl = h[t];
    int excl = incl - v;
    cur[t] = excl;
    int node = b * 256 + t;
    if (node < nNodes) rowpair[node] = make_int2(lo + excl, lo + incl);  // never spans pad gap
    __syncthreads();
    for (int i = t; i < cnt; i += 256) {
        unsigned p = packed[lo + i];
        int pos = atomicAdd(&cur[p >> 24], 1);
        if (pos < BCAP) sl[pos] = (int)(p & 0xFFFFFFu);
    }
    __syncthreads();
    for (int i = t; i < cnt; i += 256) esrc[lo + i] = sl[i];
    // pad 8 entries so layer's speculative tail reads hit a valid node id (0)
    if (t < 8 && cnt + t < BCAP) esrc[lo + cnt + t] = 0;
}

// ---------------- fused layer: gather-mean (LDS) + MFMA dual-linear ----------------
// 256 threads = 32 nodes. Phase 1: 8 lanes/node; branch-free batches of 8 edges.
// Phase 2: 4 waves x (2 row-tiles, 16 cols) MFMA over K=128 concat [mean | root].
__global__ __launch_bounds__(256) void sage_layer(
    const unsigned short* __restrict__ xb,   // gather table == root features
    const int2* __restrict__ rowpair, const int* __restrict__ esrc,
    const unsigned short* __restrict__ wcat,  // [64][128] bf16, this layer
    const float* __restrict__ bl,
    float* __restrict__ outF,                 // may be null
    unsigned short* __restrict__ outB,        // may be null
    int nNodes, int doRelu) {
    __shared__ unsigned short smean[32 * 64];  // bf16 [row][col], col ^= (row&7)<<3

    int t = threadIdx.x;
    // ---- phase 1: gather + mean ----
    {
        int nl = t >> 3;            // node local 0..31
        int q = t & 7;              // channel octet
        int lane = t & 63;
        int gbase = lane & 56;
        int node = blockIdx.x * 32 + nl;
        uint4 o = make_uint4(0, 0, 0, 0);
        if (node < nNodes) {
            int2 rp = rowpair[node];
            int rs = rp.x;
            int re = rp.y;
            float a0 = 0, a1 = 0, a2 = 0, a3 = 0, a4 = 0, a5 = 0, a6 = 0, a7 = 0;
            for (int i = rs; i < re; i += 8) {
                int mySrc = esrc[i + q];  // in-array: buckets padded by 8
                int s[8];
#pragma unroll
                for (int j = 0; j < 8; ++j) s[j] = __shfl(mySrc, gbase + j, 64);
#pragma unroll
                for (int j = 0; j < 8; ++j) {
                    uint4 w = ((const uint4*)xb)[s[j] * 8 + q];  // unconditional issue
                    if (i + j < re) {
                        a0 += __uint_as_float(w.x << 16);
                        a1 += __uint_as_float(w.x & 0xFFFF0000u);
                        a2 += __uint_as_float(w.y << 16);
                        a3 += __uint_as_float(w.y & 0xFFFF0000u);
                        a4 += __uint_as_float(w.z << 16);
                        a5 += __uint_as_float(w.z & 0xFFFF0000u);
                        a6 += __uint_as_float(w.w << 16);
                        a7 += __uint_as_float(w.w & 0xFFFF0000u);
                    }
                }
            }
            float inv = 1.0f / fmaxf((float)(re - rs), 1.0f);
            o.x = (unsigned)f2bf(a0 * inv) | ((unsigned)f2bf(a1 * inv) << 16);
            o.y = (unsigned)f2bf(a2 * inv) | ((unsigned)f2bf(a3 * inv) << 16);
            o.z = (unsigned)f2bf(a4 * inv) | ((unsigned)f2bf(a5 * inv) << 16);
            o.w = (unsigned)f2bf(a6 * inv) | ((unsigned)f2bf(a7 * inv) << 16);
        }
        int idx = nl * 64 + ((q * 8) ^ ((nl & 7) << 3));  // swizzled, 16B aligned
        *(uint4*)&smean[idx] = o;
    }
    __syncthreads();

    // ---- phase 2: MFMA ----
    int w = t >> 6;    // wave 0..3 = col group
    int l = t & 63;
    int lr = l & 15;   // A row-in-tile / B col / C col
    int lk = l >> 4;   // k-group

    const bfrag* wB = (const bfrag*)wcat;  // 16 frags per 128-k row
    int n = w * 16 + lr;                   // output channel
    bfrag b0 = wB[n * 16 + lk];
    bfrag b1 = wB[n * 16 + 4 + lk];
    bfrag b2 = wB[n * 16 + 8 + lk];
    bfrag b3 = wB[n * 16 + 12 + lk];
    float bias = bl[n];

    int base = blockIdx.x * 32;
#pragma unroll
    for (int rt = 0; rt < 2; ++rt) {
        int row0 = base + rt * 16;
        int lrow = rt * 16 + lr;
        int sw = (lrow & 7) << 3;
        bfrag a0 = *(const bfrag*)&smean[lrow * 64 + ((lk * 8) ^ sw)];
        bfrag a1 = *(const bfrag*)&smean[lrow * 64 + ((32 + lk * 8) ^ sw)];
        int grow = row0 + lr;
        if (grow >= nNodes) grow = nNodes - 1;  // clamp (stores guarded below)
        const bfrag* xr = (const bfrag*)(xb + (size_t)grow * D);
        bfrag a2 = xr[lk];
        bfrag a3 = xr[4 + lk];
        f4acc acc = {0.f, 0.f, 0.f, 0.f};
        acc = __builtin_amdgcn_mfma_f32_16x16x32_bf16(a0, b0, acc, 0, 0, 0);
        acc = __builtin_amdgcn_mfma_f32_16x16x32_bf16(a1, b1, acc, 0, 0, 0);
        acc = __builtin_amdgcn_mfma_f32_16x16x32_bf16(a2, b2, acc, 0, 0, 0);
        acc = __builtin_amdgcn_mfma_f32_16x16x32_bf16(a3, b3, acc, 0, 0, 0);
#pragma unroll
        for (int r = 0; r < 4; ++r) {
            int row = row0 + lk * 4 + r;
            if (row >= nNodes) continue;
            float v = acc[r] + bias;
            if (doRelu) v = fmaxf(v, 0.f);
            if (outF) outF[(size_t)row * D + n] = v;
            if (outB) outB[(size_t)row * D + n] = f2bf(v);
        }
    }
}

extern "C" void kernel_launch(void* const* d_in, const int* in_sizes, int n_in,
                              void* d_out, int out_size, void* d_ws, size_t ws_size,
                              hipStream_t stream) {
    const float* x   = (const float*)d_in[0];
    const int*   src = (const int*)d_in[1];
    const int*   dst = (const int*)d_in[2];
    const float* Wl0 = (const float*)d_in[3];
    const float* bl0 = (const float*)d_in[4];
    const float* Wr0 = (const float*)d_in[5];
    const float* Wl1 = (const float*)d_in[6];
    const float* bl1 = (const float*)d_in[7];
    const float* Wr1 = (const float*)d_in[8];
    const float* Wl2 = (const float*)d_in[9];
    const float* bl2 = (const float*)d_in[10];
    const float* Wr2 = (const float*)d_in[11];
    float* out = (float*)d_out;

    const size_t MB = 1 << 20;
    char* ws = (char*)d_ws;
    int* bucket_cur = (int*)(ws);                                  // NBUCK
    unsigned short* wcat = (unsigned short*)(ws + (128 << 10));    // 48 KB
    int2* rowpair = (int2*)(ws + 1 * MB);                          // NN int2 (800 KB)
    int* esrc   = (int*)(ws + 2 * MB);                             // NBUCK*BCAP (9.6 MB)
    unsigned* packed = (unsigned*)(ws + 12 * MB);                  // NBUCK*BCAP (9.6 MB, dead after p2b)
    unsigned short* hbA = (unsigned short*)(ws + 12 * MB);         // 12.8 MB (aliases packed)
    unsigned short* xb  = (unsigned short*)(ws + 26 * MB);         // 12.8 MB
    unsigned short* hbB = (unsigned short*)(ws + 39 * MB);         // 12.8 MB

    // ---- prep (f2bf + wprep + zero cursors) ----
    prep_kernel<<<F2BF_BLOCKS + WPREP_BLOCKS + ZERO_BLOCKS, 256, 0, stream>>>(
        x, xb, Wl0, Wr0, Wl1, Wr1, Wl2, Wr2, wcat, bucket_cur);

    // ---- CSR build (2 kernels: fixed-capacity buckets, no global scan) ----
    p1_partition<<<P1_BLOCKS, 256, 0, stream>>>(src, dst, bucket_cur, packed, NE);
    p2b_place<<<NBUCK, 256, 0, stream>>>(packed, bucket_cur, rowpair, esrc, NN);

    // ---- fused layers ----
    const int layerGrid = (NN + 31) / 32;
    sage_layer<<<layerGrid, 256, 0, stream>>>(xb,  rowpair, esrc, wcat,         bl0, nullptr, hbA, NN, 1);
    sage_layer<<<layerGrid, 256, 0, stream>>>(hbA, rowpair, esrc, wcat + 8192,  bl1, nullptr, hbB, NN, 1);
    sage_layer<<<layerGrid, 256, 0, stream>>>(hbB, rowpair, esrc, wcat + 16384, bl2, out, nullptr, NN, 0);
}

// Round 13
// 181.571 us; speedup vs baseline: 24.8067x; 1.0675x over previous
//
#include <hip/hip_runtime.h>

#define NN 100000
#define NE 1600000
#define D 64

#define NBUCK ((NN + 255) / 256)              // 391 buckets of 256 nodes
#define EPB 4096                               // edges per partition block
#define P1_BLOCKS ((NE + EPB - 1) / EPB)       // 391
#define BCAP 6144                              // fixed bucket capacity (avg 4096, sigma 64)

#define F2BF_BLOCKS (NN * 16 / 256)            // 6250 (NN*16 float4 elems)
#define WPREP_BLOCKS (3 * 64 * 128 / 256)      // 96
#define ZERO_BLOCKS ((NBUCK + 255) / 256)      // 2

typedef __attribute__((ext_vector_type(8))) short bfrag;   // 8 bf16 = 4 VGPR
typedef __attribute__((ext_vector_type(4))) float f4acc;   // 4 fp32 acc

__device__ __forceinline__ unsigned short f2bf(float f) {
    unsigned u = __float_as_uint(f);
    u = (u + 0x7FFFu + ((u >> 16) & 1u)) >> 16;  // RNE
    return (unsigned short)u;
}

// ---------------- prep: f2bf(x) + weight concat + zero bucket_cur, one launch ----
__global__ __launch_bounds__(256) void prep_kernel(
    const float* __restrict__ x, unsigned short* __restrict__ xb,
    const float* __restrict__ Wl0, const float* __restrict__ Wr0,
    const float* __restrict__ Wl1, const float* __restrict__ Wr1,
    const float* __restrict__ Wl2, const float* __restrict__ Wr2,
    unsigned short* __restrict__ wcat, int* __restrict__ bucket_cur) {
    int b = blockIdx.x;
    int t = threadIdx.x;
    if (b < F2BF_BLOCKS) {
        int i = b * 256 + t;  // < NN*16
        float4 v = ((const float4*)x)[i];
        ushort4 o;
        o.x = f2bf(v.x); o.y = f2bf(v.y); o.z = f2bf(v.z); o.w = f2bf(v.w);
        ((ushort4*)xb)[i] = o;
    } else if (b < F2BF_BLOCKS + WPREP_BLOCKS) {
        int i = (b - F2BF_BLOCKS) * 256 + t;  // < 3*64*128
        int layer = i >> 13;
        int rem = i & 8191;
        int n = rem >> 7;
        int k = rem & 127;
        const float* W;
        if (layer == 0) W = (k < 64) ? Wl0 : Wr0;
        else if (layer == 1) W = (k < 64) ? Wl1 : Wr1;
        else W = (k < 64) ? Wl2 : Wr2;
        wcat[i] = f2bf(W[n * 64 + (k & 63)]);
    } else {
        int i = (b - F2BF_BLOCKS - WPREP_BLOCKS) * 256 + t;
        if (i < NBUCK) bucket_cur[i] = 0;
    }
}

// ---------------- p1: partition edges into fixed-capacity bucket regions ----------
// Block-local counting sort in LDS, then coalesced run flush (bucket id staged in sb).
__global__ __launch_bounds__(256) void p1_partition(const int* __restrict__ src,
                                                    const int* __restrict__ dst,
                                                    int* __restrict__ bucket_cur,
                                                    unsigned* __restrict__ packed, int nE) {
    __shared__ int h[NBUCK];            // hist, then per-bucket reserved global offset
    __shared__ int ls[512];             // padded inclusive scan
    __shared__ int lstart[NBUCK];       // local exclusive starts
    __shared__ int lcur[NBUCK];         // local cursors
    __shared__ unsigned sl[EPB];        // staged packed words (16 KB)
    __shared__ unsigned short sb[EPB];  // staged bucket ids (8 KB)
    int t = threadIdx.x;
    for (int i = t; i < NBUCK; i += 256) h[i] = 0;
    __syncthreads();
    int base = blockIdx.x * EPB;
    int cnt = min(EPB, nE - base);
    for (int i = t; i < cnt; i += 256) atomicAdd(&h[dst[base + i] >> 8], 1);
    __syncthreads();
    // block-local inclusive scan over padded 512 (256 threads, 2 slots each)
    ls[t] = h[t];
    ls[t + 256] = (t + 256 < NBUCK) ? h[t + 256] : 0;
    __syncthreads();
    for (int off = 1; off < 512; off <<= 1) {
        int a = (t >= off) ? ls[t - off] : 0;
        int b2 = (t + 256 >= off) ? ls[t + 256 - off] : 0;
        __syncthreads();
        ls[t] += a;
        ls[t + 256] += b2;
        __syncthreads();
    }
    // exclusive starts, local cursors, global range reservation
    for (int i = t; i < NBUCK; i += 256) {
        int c = h[i];
        int excl = ls[i] - c;
        lstart[i] = excl;
        lcur[i] = excl;
        h[i] = c ? atomicAdd(&bucket_cur[i], c) : 0;  // offset within bucket region
    }
    __syncthreads();
    // place into staging (bucket-sorted within block), record bucket id
    for (int i = t; i < cnt; i += 256) {
        int d = dst[base + i];
        int bk = d >> 8;
        int pos = atomicAdd(&lcur[bk], 1);
        sl[pos] = ((unsigned)(d & 255) << 24) | (unsigned)src[base + i];
        sb[pos] = (unsigned short)bk;
    }
    __syncthreads();
    // flush: contiguous per-bucket runs -> packed[b*BCAP + reserved + run-offset]
    for (int j = t; j < cnt; j += 256) {
        int bk = sb[j];
        packed[bk * BCAP + h[bk] + (j - lstart[bk])] = sl[j];
    }
}

// p2b: per-bucket hist + local scan -> rowpair(start,end); in-LDS sort -> esrc (+pad 16)
__global__ __launch_bounds__(256) void p2b_place(const unsigned* __restrict__ packed,
                                                 const int* __restrict__ bucket_cur,
                                                 int2* __restrict__ rowpair,
                                                 int* __restrict__ esrc, int nNodes) {
    __shared__ int h[256];
    __shared__ int cur[256];
    __shared__ int sl[BCAP];
    int b = blockIdx.x, t = threadIdx.x;
    h[t] = 0;
    __syncthreads();
    int lo = b * BCAP;
    int cnt = bucket_cur[b];
    for (int i = t; i < cnt; i += 256) atomicAdd(&h[packed[lo + i] >> 24], 1);
    __syncthreads();
    int v = h[t];
    for (int off = 1; off < 256; off <<= 1) {
        int u = (t >= off) ? h[t - off] : 0;
        __syncthreads();
        h[t] += u;
        __syncthreads();
    }
    int incl = h[t];
    int excl = incl - v;
    cur[t] = excl;
    int node = b * 256 + t;
    if (node < nNodes) rowpair[node] = make_int2(lo + excl, lo + incl);  // never spans pad gap
    __syncthreads();
    for (int i = t; i < cnt; i += 256) {
        unsigned p = packed[lo + i];
        int pos = atomicAdd(&cur[p >> 24], 1);
        if (pos < BCAP) sl[pos] = (int)(p & 0xFFFFFFu);
    }
    __syncthreads();
    for (int i = t; i < cnt; i += 256) esrc[lo + i] = sl[i];
    // pad 16 entries so layer's speculative 16-slot tail reads hit a valid node id (0)
    if (t < 16 && cnt + t < BCAP) esrc[lo + cnt + t] = 0;
}

// ---------------- fused layer: gather-mean (LDS) + MFMA dual-linear ----------------
// 256 threads = 32 nodes. Phase 1: 8 lanes/node; 16-slot batches, clamped-dedup tail
// (out-of-range slots re-fetch last valid row -> requests merge; no wasted lines).
// Phase 2: 4 waves x (2 row-tiles, 16 cols) MFMA over K=128 concat [mean | root].
__global__ __launch_bounds__(256) void sage_layer(
    const unsigned short* __restrict__ xb,   // gather table == root features
    const int2* __restrict__ rowpair, const int* __restrict__ esrc,
    const unsigned short* __restrict__ wcat,  // [64][128] bf16, this layer
    const float* __restrict__ bl,
    float* __restrict__ outF,                 // may be null
    unsigned short* __restrict__ outB,        // may be null
    int nNodes, int doRelu) {
    __shared__ unsigned short smean[32 * 64];  // bf16 [row][col], col ^= (row&7)<<3

    int t = threadIdx.x;
    // ---- phase 1: gather + mean ----
    {
        int nl = t >> 3;            // node local 0..31
        int q = t & 7;              // channel octet
        int lane = t & 63;
        int gbase = lane & 56;
        int node = blockIdx.x * 32 + nl;
        uint4 o = make_uint4(0, 0, 0, 0);
        if (node < nNodes) {
            int2 rp = rowpair[node];
            int rs = rp.x;
            int re = rp.y;
            float a0 = 0, a1 = 0, a2 = 0, a3 = 0, a4 = 0, a5 = 0, a6 = 0, a7 = 0;
            for (int i = rs; i < re; i += 16) {
                int mA = esrc[i + q];       // slots 0..7   (coalesced per group)
                int mB = esrc[i + 8 + q];   // slots 8..15  (bucket padded by 16)
                int rem = re - i;           // uniform per 8-lane group, >0
                int s[16];
#pragma unroll
                for (int j = 0; j < 16; ++j) {
                    int jj = min(j, rem - 1);             // clamp: dup last valid edge
                    int sa = __shfl(mA, gbase + (jj & 7), 64);
                    int sb2 = __shfl(mB, gbase + (jj & 7), 64);
                    s[j] = (jj < 8) ? sa : sb2;
                }
#pragma unroll
                for (int j = 0; j < 16; ++j) {
                    uint4 w = ((const uint4*)xb)[s[j] * 8 + q];  // dup slots merge in L2
                    if (i + j < re) {
                        a0 += __uint_as_float(w.x << 16);
                        a1 += __uint_as_float(w.x & 0xFFFF0000u);
                        a2 += __uint_as_float(w.y << 16);
                        a3 += __uint_as_float(w.y & 0xFFFF0000u);
                        a4 += __uint_as_float(w.z << 16);
                        a5 += __uint_as_float(w.z & 0xFFFF0000u);
                        a6 += __uint_as_float(w.w << 16);
                        a7 += __uint_as_float(w.w & 0xFFFF0000u);
                    }
                }
            }
            float inv = 1.0f / fmaxf((float)(re - rs), 1.0f);
            o.x = (unsigned)f2bf(a0 * inv) | ((unsigned)f2bf(a1 * inv) << 16);
            o.y = (unsigned)f2bf(a2 * inv) | ((unsigned)f2bf(a3 * inv) << 16);
            o.z = (unsigned)f2bf(a4 * inv) | ((unsigned)f2bf(a5 * inv) << 16);
            o.w = (unsigned)f2bf(a6 * inv) | ((unsigned)f2bf(a7 * inv) << 16);
        }
        int idx = nl * 64 + ((q * 8) ^ ((nl & 7) << 3));  // swizzled, 16B aligned
        *(uint4*)&smean[idx] = o;
    }
    __syncthreads();

    // ---- phase 2: MFMA ----
    int w = t >> 6;    // wave 0..3 = col group
    int l = t & 63;
    int lr = l & 15;   // A row-in-tile / B col / C col
    int lk = l >> 4;   // k-group

    const bfrag* wB = (const bfrag*)wcat;  // 16 frags per 128-k row
    int n = w * 16 + lr;                   // output channel
    bfrag b0 = wB[n * 16 + lk];
    bfrag b1 = wB[n * 16 + 4 + lk];
    bfrag b2 = wB[n * 16 + 8 + lk];
    bfrag b3 = wB[n * 16 + 12 + lk];
    float bias = bl[n];

    int base = blockIdx.x * 32;
#pragma unroll
    for (int rt = 0; rt < 2; ++rt) {
        int row0 = base + rt * 16;
        int lrow = rt * 16 + lr;
        int sw = (lrow & 7) << 3;
        bfrag a0 = *(const bfrag*)&smean[lrow * 64 + ((lk * 8) ^ sw)];
        bfrag a1 = *(const bfrag*)&smean[lrow * 64 + ((32 + lk * 8) ^ sw)];
        int grow = row0 + lr;
        if (grow >= nNodes) grow = nNodes - 1;  // clamp (stores guarded below)
        const bfrag* xr = (const bfrag*)(xb + (size_t)grow * D);
        bfrag a2 = xr[lk];
        bfrag a3 = xr[4 + lk];
        f4acc acc = {0.f, 0.f, 0.f, 0.f};
        acc = __builtin_amdgcn_mfma_f32_16x16x32_bf16(a0, b0, acc, 0, 0, 0);
        acc = __builtin_amdgcn_mfma_f32_16x16x32_bf16(a1, b1, acc, 0, 0, 0);
        acc = __builtin_amdgcn_mfma_f32_16x16x32_bf16(a2, b2, acc, 0, 0, 0);
        acc = __builtin_amdgcn_mfma_f32_16x16x32_bf16(a3, b3, acc, 0, 0, 0);
#pragma unroll
        for (int r = 0; r < 4; ++r) {
            int row = row0 + lk * 4 + r;
            if (row >= nNodes) continue;
            float v = acc[r] + bias;
            if (doRelu) v = fmaxf(v, 0.f);
            if (outF) outF[(size_t)row * D + n] = v;
            if (outB) outB[(size_t)row * D + n] = f2bf(v);
        }
    }
}

extern "C" void kernel_launch(void* const* d_in, const int* in_sizes, int n_in,
                              void* d_out, int out_size, void* d_ws, size_t ws_size,
                              hipStream_t stream) {
    const float* x   = (const float*)d_in[0];
    const int*   src = (const int*)d_in[1];
    const int*   dst = (const int*)d_in[2];
    const float* Wl0 = (const float*)d_in[3];
    const float* bl0 = (const float*)d_in[4];
    const float* Wr0 = (const float*)d_in[5];
    const float* Wl1 = (const float*)d_in[6];
    const float* bl1 = (const float*)d_in[7];
    const float* Wr1 = (const float*)d_in[8];
    const float* Wl2 = (const float*)d_in[9];
    const float* bl2 = (const float*)d_in[10];
    const float* Wr2 = (const float*)d_in[11];
    float* out = (float*)d_out;

    const size_t MB = 1 << 20;
    char* ws = (char*)d_ws;
    int* bucket_cur = (int*)(ws);                                  // NBUCK
    unsigned short* wcat = (unsigned short*)(ws + (128 << 10));    // 48 KB
    int2* rowpair = (int2*)(ws + 1 * MB);                          // NN int2 (800 KB)
    int* esrc   = (int*)(ws + 2 * MB);                             // NBUCK*BCAP (9.6 MB)
    unsigned* packed = (unsigned*)(ws + 12 * MB);                  // NBUCK*BCAP (9.6 MB, dead after p2b)
    unsigned short* hbA = (unsigned short*)(ws + 12 * MB);         // 12.8 MB (aliases packed)
    unsigned short* xb  = (unsigned short*)(ws + 26 * MB);         // 12.8 MB
    unsigned short* hbB = (unsigned short*)(ws + 39 * MB);         // 12.8 MB

    // ---- prep (f2bf + wprep + zero cursors) ----
    prep_kernel<<<F2BF_BLOCKS + WPREP_BLOCKS + ZERO_BLOCKS, 256, 0, stream>>>(
        x, xb, Wl0, Wr0, Wl1, Wr1, Wl2, Wr2, wcat, bucket_cur);

    // ---- CSR build (2 kernels: fixed-capacity buckets, no global scan) ----
    p1_partition<<<P1_BLOCKS, 256, 0, stream>>>(src, dst, bucket_cur, packed, NE);
    p2b_place<<<NBUCK, 256, 0, stream>>>(packed, bucket_cur, rowpair, esrc, NN);

    // ---- fused layers ----
    const int layerGrid = (NN + 31) / 32;
    sage_layer<<<layerGrid, 256, 0, stream>>>(xb,  rowpair, esrc, wcat,         bl0, nullptr, hbA, NN, 1);
    sage_layer<<<layerGrid, 256, 0, stream>>>(hbA, rowpair, esrc, wcat + 8192,  bl1, nullptr, hbB, NN, 1);
    sage_layer<<<layerGrid, 256, 0, stream>>>(hbB, rowpair, esrc, wcat + 16384, bl2, out, nullptr, NN, 0);
}

// Round 14
// 177.471 us; speedup vs baseline: 25.3799x; 1.0231x over previous
//
#include <hip/hip_runtime.h>

#define NN 100000
#define NE 1600000
#define D 64

#define NBUCK ((NN + 255) / 256)              // 391 buckets of 256 nodes
#define EPB 4096                               // edges per partition block
#define P1_BLOCKS ((NE + EPB - 1) / EPB)       // 391
#define BCAP 6144                              // fixed bucket capacity (avg 4096, sigma 64)

#define F2BF_BLOCKS (NN * 16 / 256)            // 6250 (NN*16 float4 elems)
#define WPREP_BLOCKS (3 * 64 * 128 / 256)      // 96

typedef __attribute__((ext_vector_type(8))) short bfrag;   // 8 bf16 = 4 VGPR
typedef __attribute__((ext_vector_type(4))) float f4acc;   // 4 fp32 acc

__device__ __forceinline__ unsigned short f2bf(float f) {
    unsigned u = __float_as_uint(f);
    u = (u + 0x7FFFu + ((u >> 16) & 1u)) >> 16;  // RNE
    return (unsigned short)u;
}

// ---------------- p1 + prep fused: partition edges (blocks 0..P1_BLOCKS-1),
// f2bf(x) + weight concat (remaining blocks). bucket_cur pre-zeroed by memset.
__global__ __launch_bounds__(256) void p1prep_kernel(
    const int* __restrict__ src, const int* __restrict__ dst,
    int* __restrict__ bucket_cur, unsigned* __restrict__ packed,
    const float* __restrict__ x, unsigned short* __restrict__ xb,
    const float* __restrict__ Wl0, const float* __restrict__ Wr0,
    const float* __restrict__ Wl1, const float* __restrict__ Wr1,
    const float* __restrict__ Wl2, const float* __restrict__ Wr2,
    unsigned short* __restrict__ wcat) {
    int b = blockIdx.x;
    int t = threadIdx.x;
    if (b >= P1_BLOCKS) {
        int pb = b - P1_BLOCKS;
        if (pb < F2BF_BLOCKS) {
            int i = pb * 256 + t;  // < NN*16
            float4 v = ((const float4*)x)[i];
            ushort4 o;
            o.x = f2bf(v.x); o.y = f2bf(v.y); o.z = f2bf(v.z); o.w = f2bf(v.w);
            ((ushort4*)xb)[i] = o;
        } else {
            int i = (pb - F2BF_BLOCKS) * 256 + t;  // < 3*64*128
            int layer = i >> 13;
            int rem = i & 8191;
            int n = rem >> 7;
            int k = rem & 127;
            const float* W;
            if (layer == 0) W = (k < 64) ? Wl0 : Wr0;
            else if (layer == 1) W = (k < 64) ? Wl1 : Wr1;
            else W = (k < 64) ? Wl2 : Wr2;
            wcat[i] = f2bf(W[n * 64 + (k & 63)]);
        }
        return;
    }
    // ---- p1 partition ----
    __shared__ int h[NBUCK];            // hist, then per-bucket reserved global offset
    __shared__ int ls[512];             // padded inclusive scan
    __shared__ int lstart[NBUCK];       // local exclusive starts
    __shared__ int lcur[NBUCK];         // local cursors
    __shared__ unsigned sl[EPB];        // staged packed words (16 KB)
    __shared__ unsigned short sb[EPB];  // staged bucket ids (8 KB)
    for (int i = t; i < NBUCK; i += 256) h[i] = 0;
    __syncthreads();
    int base = b * EPB;
    int cnt = min(EPB, NE - base);
    for (int i = t; i < cnt; i += 256) atomicAdd(&h[dst[base + i] >> 8], 1);
    __syncthreads();
    ls[t] = h[t];
    ls[t + 256] = (t + 256 < NBUCK) ? h[t + 256] : 0;
    __syncthreads();
    for (int off = 1; off < 512; off <<= 1) {
        int a = (t >= off) ? ls[t - off] : 0;
        int b2 = (t + 256 >= off) ? ls[t + 256 - off] : 0;
        __syncthreads();
        ls[t] += a;
        ls[t + 256] += b2;
        __syncthreads();
    }
    for (int i = t; i < NBUCK; i += 256) {
        int c = h[i];
        int excl = ls[i] - c;
        lstart[i] = excl;
        lcur[i] = excl;
        h[i] = c ? atomicAdd(&bucket_cur[i], c) : 0;  // offset within bucket region
    }
    __syncthreads();
    for (int i = t; i < cnt; i += 256) {
        int d = dst[base + i];
        int bk = d >> 8;
        int pos = atomicAdd(&lcur[bk], 1);
        sl[pos] = ((unsigned)(d & 255) << 24) | (unsigned)src[base + i];
        sb[pos] = (unsigned short)bk;
    }
    __syncthreads();
    for (int j = t; j < cnt; j += 256) {
        int bk = sb[j];
        packed[bk * BCAP + h[bk] + (j - lstart[bk])] = sl[j];
    }
}

// p2b: per-bucket hist + local scan -> rowpair(start,end); in-LDS sort -> esrc (+pad 16)
__global__ __launch_bounds__(256) void p2b_place(const unsigned* __restrict__ packed,
                                                 const int* __restrict__ bucket_cur,
                                                 int2* __restrict__ rowpair,
                                                 int* __restrict__ esrc, int nNodes) {
    __shared__ int h[256];
    __shared__ int cur[256];
    __shared__ int sl[BCAP];
    int b = blockIdx.x, t = threadIdx.x;
    h[t] = 0;
    __syncthreads();
    int lo = b * BCAP;
    int cnt = bucket_cur[b];
    for (int i = t; i < cnt; i += 256) atomicAdd(&h[packed[lo + i] >> 24], 1);
    __syncthreads();
    int v = h[t];
    for (int off = 1; off < 256; off <<= 1) {
        int u = (t >= off) ? h[t - off] : 0;
        __syncthreads();
        h[t] += u;
        __syncthreads();
    }
    int incl = h[t];
    int excl = incl - v;
    cur[t] = excl;
    int node = b * 256 + t;
    if (node < nNodes) rowpair[node] = make_int2(lo + excl, lo + incl);  // never spans pad gap
    __syncthreads();
    for (int i = t; i < cnt; i += 256) {
        unsigned p = packed[lo + i];
        int pos = atomicAdd(&cur[p >> 24], 1);
        if (pos < BCAP) sl[pos] = (int)(p & 0xFFFFFFu);
    }
    __syncthreads();
    for (int i = t; i < cnt; i += 256) esrc[lo + i] = sl[i];
    if (t < 16 && cnt + t < BCAP) esrc[lo + cnt + t] = 0;
}

// ---------------- fused layer: gather-mean (LDS) + MFMA dual-linear ----------------
// 256 threads = 32 nodes. Phase 1: 8 lanes/node; 16-slot batches, clamped-dedup tail.
// Phase 2: 4 waves x (2 row-tiles, 16 cols) MFMA over K=128 concat [mean | root].
// Epilogue: acc -> swizzled LDS tile -> fully coalesced global write (no partial lines).
__global__ __launch_bounds__(256) void sage_layer(
    const unsigned short* __restrict__ xb,   // gather table == root features
    const int2* __restrict__ rowpair, const int* __restrict__ esrc,
    const unsigned short* __restrict__ wcat,  // [64][128] bf16, this layer
    const float* __restrict__ bl,
    float* __restrict__ outF,                 // final layer (else null)
    unsigned short* __restrict__ outB,        // hidden layers (else null)
    int nNodes, int doRelu) {
    __shared__ unsigned short smean[32 * 64];  // bf16 [row][col], col ^= (row&7)<<3
    __shared__ float tf[32 * 64];              // f32 epilogue tile (final layer)

    int t = threadIdx.x;
    // ---- phase 1: gather + mean ----
    {
        int nl = t >> 3;            // node local 0..31
        int q = t & 7;              // channel octet
        int lane = t & 63;
        int gbase = lane & 56;
        int node = blockIdx.x * 32 + nl;
        uint4 o = make_uint4(0, 0, 0, 0);
        if (node < nNodes) {
            int2 rp = rowpair[node];
            int rs = rp.x;
            int re = rp.y;
            float a0 = 0, a1 = 0, a2 = 0, a3 = 0, a4 = 0, a5 = 0, a6 = 0, a7 = 0;
            for (int i = rs; i < re; i += 16) {
                int mA = esrc[i + q];       // slots 0..7   (coalesced per group)
                int mB = esrc[i + 8 + q];   // slots 8..15  (bucket padded by 16)
                int rem = re - i;           // uniform per 8-lane group, >0
                int s[16];
#pragma unroll
                for (int j = 0; j < 16; ++j) {
                    int jj = min(j, rem - 1);             // clamp: dup last valid edge
                    int sa = __shfl(mA, gbase + (jj & 7), 64);
                    int sb2 = __shfl(mB, gbase + (jj & 7), 64);
                    s[j] = (jj < 8) ? sa : sb2;
                }
#pragma unroll
                for (int j = 0; j < 16; ++j) {
                    uint4 w = ((const uint4*)xb)[s[j] * 8 + q];  // dup slots merge in L2
                    if (i + j < re) {
                        a0 += __uint_as_float(w.x << 16);
                        a1 += __uint_as_float(w.x & 0xFFFF0000u);
                        a2 += __uint_as_float(w.y << 16);
                        a3 += __uint_as_float(w.y & 0xFFFF0000u);
                        a4 += __uint_as_float(w.z << 16);
                        a5 += __uint_as_float(w.z & 0xFFFF0000u);
                        a6 += __uint_as_float(w.w << 16);
                        a7 += __uint_as_float(w.w & 0xFFFF0000u);
                    }
                }
            }
            float inv = 1.0f / fmaxf((float)(re - rs), 1.0f);
            o.x = (unsigned)f2bf(a0 * inv) | ((unsigned)f2bf(a1 * inv) << 16);
            o.y = (unsigned)f2bf(a2 * inv) | ((unsigned)f2bf(a3 * inv) << 16);
            o.z = (unsigned)f2bf(a4 * inv) | ((unsigned)f2bf(a5 * inv) << 16);
            o.w = (unsigned)f2bf(a6 * inv) | ((unsigned)f2bf(a7 * inv) << 16);
        }
        int idx = nl * 64 + ((q * 8) ^ ((nl & 7) << 3));  // swizzled, 16B aligned
        *(uint4*)&smean[idx] = o;
    }
    __syncthreads();

    // ---- phase 2: MFMA ----
    int w = t >> 6;    // wave 0..3 = col group
    int l = t & 63;
    int lr = l & 15;   // A row-in-tile / B col / C col
    int lk = l >> 4;   // k-group

    const bfrag* wB = (const bfrag*)wcat;  // 16 frags per 128-k row
    int n = w * 16 + lr;                   // output channel
    bfrag b0 = wB[n * 16 + lk];
    bfrag b1 = wB[n * 16 + 4 + lk];
    bfrag b2 = wB[n * 16 + 8 + lk];
    bfrag b3 = wB[n * 16 + 12 + lk];
    float bias = bl[n];

    int base = blockIdx.x * 32;
    f4acc accv[2];
#pragma unroll
    for (int rt = 0; rt < 2; ++rt) {
        int row0 = base + rt * 16;
        int lrow = rt * 16 + lr;
        int sw = (lrow & 7) << 3;
        bfrag a0 = *(const bfrag*)&smean[lrow * 64 + ((lk * 8) ^ sw)];
        bfrag a1 = *(const bfrag*)&smean[lrow * 64 + ((32 + lk * 8) ^ sw)];
        int grow = row0 + lr;
        if (grow >= nNodes) grow = nNodes - 1;  // clamp (writes guarded in epilogue)
        const bfrag* xr = (const bfrag*)(xb + (size_t)grow * D);
        bfrag a2 = xr[lk];
        bfrag a3 = xr[4 + lk];
        f4acc acc = {0.f, 0.f, 0.f, 0.f};
        acc = __builtin_amdgcn_mfma_f32_16x16x32_bf16(a0, b0, acc, 0, 0, 0);
        acc = __builtin_amdgcn_mfma_f32_16x16x32_bf16(a1, b1, acc, 0, 0, 0);
        acc = __builtin_amdgcn_mfma_f32_16x16x32_bf16(a2, b2, acc, 0, 0, 0);
        acc = __builtin_amdgcn_mfma_f32_16x16x32_bf16(a3, b3, acc, 0, 0, 0);
        accv[rt] = acc;
    }
    __syncthreads();  // smean reads done; tiles reusable

    // ---- epilogue: coalesced store via swizzled LDS tile ----
    if (outB) {
#pragma unroll
        for (int rt = 0; rt < 2; ++rt)
#pragma unroll
            for (int r = 0; r < 4; ++r) {
                int row = rt * 16 + lk * 4 + r;  // 0..31
                float v = accv[rt][r] + bias;
                if (doRelu) v = fmaxf(v, 0.f);
                smean[row * 64 + (n ^ ((row & 7) << 3))] = f2bf(v);
            }
        __syncthreads();
        int row = t >> 3;
        int node = base + row;
        int c8 = t & 7;
        if (node < nNodes) {
            uint4 v = *(uint4*)&smean[row * 64 + ((c8 ^ (row & 7)) * 8)];
            ((uint4*)outB)[(size_t)node * 8 + c8] = v;   // 16B coalesced
        }
    } else {
#pragma unroll
        for (int rt = 0; rt < 2; ++rt)
#pragma unroll
            for (int r = 0; r < 4; ++r) {
                int row = rt * 16 + lk * 4 + r;
                float v = accv[rt][r] + bias;
                if (doRelu) v = fmaxf(v, 0.f);
                tf[row * 64 + (n ^ ((row & 7) << 3))] = v;
            }
        __syncthreads();
        int row = t >> 3;
        int node = base + row;
        int c8 = t & 7;
        if (node < nNodes) {
            int cs = (c8 ^ (row & 7)) * 8;
            float4 v0 = *(float4*)&tf[row * 64 + cs];
            float4 v1 = *(float4*)&tf[row * 64 + cs + 4];
            ((float4*)outF)[(size_t)node * 16 + c8 * 2 + 0] = v0;  // 32B coalesced
            ((float4*)outF)[(size_t)node * 16 + c8 * 2 + 1] = v1;
        }
    }
}

extern "C" void kernel_launch(void* const* d_in, const int* in_sizes, int n_in,
                              void* d_out, int out_size, void* d_ws, size_t ws_size,
                              hipStream_t stream) {
    const float* x   = (const float*)d_in[0];
    const int*   src = (const int*)d_in[1];
    const int*   dst = (const int*)d_in[2];
    const float* Wl0 = (const float*)d_in[3];
    const float* bl0 = (const float*)d_in[4];
    const float* Wr0 = (const float*)d_in[5];
    const float* Wl1 = (const float*)d_in[6];
    const float* bl1 = (const float*)d_in[7];
    const float* Wr1 = (const float*)d_in[8];
    const float* Wl2 = (const float*)d_in[9];
    const float* bl2 = (const float*)d_in[10];
    const float* Wr2 = (const float*)d_in[11];
    float* out = (float*)d_out;

    const size_t MB = 1 << 20;
    char* ws = (char*)d_ws;
    int* bucket_cur = (int*)(ws);                                  // NBUCK
    unsigned short* wcat = (unsigned short*)(ws + (128 << 10));    // 48 KB
    int2* rowpair = (int2*)(ws + 1 * MB);                          // NN int2 (800 KB)
    int* esrc   = (int*)(ws + 2 * MB);                             // NBUCK*BCAP (9.6 MB)
    unsigned* packed = (unsigned*)(ws + 12 * MB);                  // NBUCK*BCAP (9.6 MB, dead after p2b)
    unsigned short* hbA = (unsigned short*)(ws + 12 * MB);         // 12.8 MB (aliases packed)
    unsigned short* xb  = (unsigned short*)(ws + 26 * MB);         // 12.8 MB
    unsigned short* hbB = (unsigned short*)(ws + 39 * MB);         // 12.8 MB

    // zero bucket cursors (1.5 KB — cheap; R7/R8 fill rows were harness poison)
    hipMemsetAsync(bucket_cur, 0, (size_t)NBUCK * sizeof(int), stream);

    // ---- fused prep + partition ----
    p1prep_kernel<<<P1_BLOCKS + F2BF_BLOCKS + WPREP_BLOCKS, 256, 0, stream>>>(
        src, dst, bucket_cur, packed, x, xb, Wl0, Wr0, Wl1, Wr1, Wl2, Wr2, wcat);
    p2b_place<<<NBUCK, 256, 0, stream>>>(packed, bucket_cur, rowpair, esrc, NN);

    // ---- fused layers ----
    const int layerGrid = (NN + 31) / 32;
    sage_layer<<<layerGrid, 256, 0, stream>>>(xb,  rowpair, esrc, wcat,         bl0, nullptr, hbA, NN, 1);
    sage_layer<<<layerGrid, 256, 0, stream>>>(hbA, rowpair, esrc, wcat + 8192,  bl1, nullptr, hbB, NN, 1);
    sage_layer<<<layerGrid, 256, 0, stream>>>(hbB, rowpair, esrc, wcat + 16384, bl2, out, nullptr, NN, 0);
}